// Round 7
// baseline (562.023 us; speedup 1.0000x reference)
//
#include <hip/hip_runtime.h>
#include <math.h>

typedef unsigned short u16;
typedef unsigned int   u32;
typedef __bf16 bf16x8 __attribute__((ext_vector_type(8)));
typedef float  f32x4  __attribute__((ext_vector_type(4)));

#define S_LEN 4096
#define HID   2048
#define NHEAD 16
#define HD    128
#define NW    1024
#define TOK   8192
#define LN10000 9.2103403719761836f
#define NEG_BIG (-1e30f)

__device__ __forceinline__ float b2f(u16 u){
  union { u32 i; float f; } v; v.i = ((u32)u) << 16; return v.f;
}
__device__ __forceinline__ u16 f2b(float f){
  union { float f; u32 i; } v; v.f = f;
  return (u16)((v.i + 0x7FFFu + ((v.i >> 16) & 1u)) >> 16);
}

// ---------------- one-time f32 -> bf16 convert (hidden), 8 elems/thread -----------------
__global__ __launch_bounds__(256) void cvt_bf16(const float* __restrict__ in,
                                                u16* __restrict__ out){
  size_t i = (size_t)blockIdx.x*256 + threadIdx.x;
  float4 a = ((const float4*)in)[2*i];
  float4 b = ((const float4*)in)[2*i+1];
  u16 t[8];
  t[0]=f2b(a.x); t[1]=f2b(a.y); t[2]=f2b(a.z); t[3]=f2b(a.w);
  t[4]=f2b(b.x); t[5]=f2b(b.y); t[6]=f2b(b.z); t[7]=f2b(b.w);
  *(uint4*)&out[i*8] = *(uint4*)t;
}

// ---------------- one-time weight transpose+convert: f32[K][N] -> bf16[N][K] ------------
__global__ __launch_bounds__(256) void transpose_w(const float* __restrict__ in,
    u16* __restrict__ out, int K, int N){
  __shared__ float t[32][33];
  const int n0 = blockIdx.x*32, k0 = blockIdx.y*32;
  const int c = threadIdx.x & 31, r8 = threadIdx.x >> 5;
  #pragma unroll
  for (int i = 0; i < 4; i++)
    t[r8 + i*8][c] = in[(size_t)(k0 + r8 + i*8)*N + n0 + c];
  __syncthreads();
  #pragma unroll
  for (int i = 0; i < 4; i++)
    out[(size_t)(n0 + r8 + i*8)*K + k0 + c] = f2b(t[c][r8 + i*8]);
}

typedef __attribute__((address_space(3))) u16 as3_u16;
typedef __attribute__((address_space(1))) const u16 as1_u16;
__device__ __forceinline__ void gload16(const u16* g, u16* l){
  __builtin_amdgcn_global_load_lds((as1_u16*)g, (as3_u16*)l, 16, 0, 0);
}

// ---------------- 256x256 8-phase GEMM (T2+T3+T4+T5): C = A(M,K) @ Bt(N,K)^T ------------
// Unchanged from R5 (harness-verified). BK=64, 8 waves, 128KB LDS dbuf, counted vmcnt,
// both-sides XOR swizzle, setprio around MFMA clusters.
template<typename TC>
__global__ __launch_bounds__(512, 1) void gemm256(const u16* __restrict__ A,
    const u16* __restrict__ Bt, TC* __restrict__ C, int M, int N, int K)
{
  __shared__ __align__(16) u16 LA[2][256*64];
  __shared__ __align__(16) u16 LB[2][256*64];
  const int tid  = threadIdx.x;
  const int lane = tid & 63;
  const int w    = tid >> 6;        // 0..7
  const int wm   = w & 1;
  const int wn   = w >> 1;          // 0..3
  const int lrw  = lane & 15;
  const int quad = lane >> 4;
  const int NB   = N >> 8;
  const int nwg  = gridDim.x;
  const int bid  = blockIdx.x;
  const int swz  = (bid & 7) * (nwg >> 3) + (bid >> 3);
  const int bN   = (swz % NB) << 8;
  const int bM   = (swz / NB) << 8;

  const int rlo = lane >> 3;
  const int csw = ((lane & 7) ^ rlo) << 3;
  const int sr0 = w * 16;
  const int swr = (lrw & 7) << 3;
  const u16* Ag = A  + (size_t)bM * K + (size_t)rlo * K + csw;
  const u16* Bg = Bt + (size_t)bN * K + (size_t)rlo * K + csw;
  const size_t rK = (size_t)K;

  f32x4 acc[8][4];
  #pragma unroll
  for (int i = 0; i < 8; i++)
    #pragma unroll
    for (int j = 0; j < 4; j++)
      #pragma unroll
      for (int r = 0; r < 4; r++) acc[i][j][r] = 0.f;

  const int NT = K >> 6;

  gload16(Ag + (size_t)(  0 + sr0    )*rK, &LA[0][(  0 + sr0    )*64]);
  gload16(Ag + (size_t)(  0 + sr0 + 8)*rK, &LA[0][(  0 + sr0 + 8)*64]);
  gload16(Bg + (size_t)(  0 + sr0    )*rK, &LB[0][(  0 + sr0    )*64]);
  gload16(Bg + (size_t)(  0 + sr0 + 8)*rK, &LB[0][(  0 + sr0 + 8)*64]);
  gload16(Bg + (size_t)(128 + sr0    )*rK, &LB[0][(128 + sr0    )*64]);
  gload16(Bg + (size_t)(128 + sr0 + 8)*rK, &LB[0][(128 + sr0 + 8)*64]);
  gload16(Ag + (size_t)(128 + sr0    )*rK, &LA[0][(128 + sr0    )*64]);
  gload16(Ag + (size_t)(128 + sr0 + 8)*rK, &LA[0][(128 + sr0 + 8)*64]);
  asm volatile("s_waitcnt vmcnt(2)" ::: "memory");
  __builtin_amdgcn_s_barrier();
  __builtin_amdgcn_sched_barrier(0);

  for (int t = 0; t < NT; ++t){
    const int cur = t & 1, nxt = cur ^ 1;
    const int kn  = ((t + 1) & (NT - 1)) << 6;
    const u16* la = &LA[cur][0];
    const u16* lb = &LB[cur][0];
    u16* sa = &LA[nxt][0];
    u16* sb = &LB[nxt][0];

    bf16x8 bfr[4][2], afr[2][2];

    // ---- phase 0
    gload16(Ag + (size_t)(  0 + sr0    )*rK + kn, &sa[(  0 + sr0    )*64]);
    gload16(Ag + (size_t)(  0 + sr0 + 8)*rK + kn, &sa[(  0 + sr0 + 8)*64]);
    gload16(Bg + (size_t)(  0 + sr0    )*rK + kn, &sb[(  0 + sr0    )*64]);
    gload16(Bg + (size_t)(  0 + sr0 + 8)*rK + kn, &sb[(  0 + sr0 + 8)*64]);
    #pragma unroll
    for (int nf = 0; nf < 4; nf++)
      #pragma unroll
      for (int kh = 0; kh < 2; kh++)
        bfr[nf][kh] = *(const bf16x8*)&lb[(wn*16 + nf*64 + lrw)*64 + ((kh*32 + quad*8) ^ swr)];
    #pragma unroll
    for (int i = 0; i < 2; i++)
      #pragma unroll
      for (int kh = 0; kh < 2; kh++)
        afr[i][kh] = *(const bf16x8*)&la[(wm*16 + (0+i)*32 + lrw)*64 + ((kh*32 + quad*8) ^ swr)];
    __builtin_amdgcn_s_barrier();
    __builtin_amdgcn_sched_barrier(0);
    __builtin_amdgcn_s_setprio(1);
    #pragma unroll
    for (int i = 0; i < 2; i++)
      #pragma unroll
      for (int nf = 0; nf < 4; nf++)
        #pragma unroll
        for (int kh = 0; kh < 2; kh++)
          acc[0+i][nf] = __builtin_amdgcn_mfma_f32_16x16x32_bf16(afr[i][kh], bfr[nf][kh], acc[0+i][nf], 0, 0, 0);
    __builtin_amdgcn_s_setprio(0);
    __builtin_amdgcn_s_barrier();
    __builtin_amdgcn_sched_barrier(0);

    // ---- phase 1
    gload16(Bg + (size_t)(128 + sr0    )*rK + kn, &sb[(128 + sr0    )*64]);
    gload16(Bg + (size_t)(128 + sr0 + 8)*rK + kn, &sb[(128 + sr0 + 8)*64]);
    #pragma unroll
    for (int i = 0; i < 2; i++)
      #pragma unroll
      for (int kh = 0; kh < 2; kh++)
        afr[i][kh] = *(const bf16x8*)&la[(wm*16 + (2+i)*32 + lrw)*64 + ((kh*32 + quad*8) ^ swr)];
    asm volatile("s_waitcnt vmcnt(6)" ::: "memory");
    __builtin_amdgcn_s_barrier();
    __builtin_amdgcn_sched_barrier(0);
    __builtin_amdgcn_s_setprio(1);
    #pragma unroll
    for (int i = 0; i < 2; i++)
      #pragma unroll
      for (int nf = 0; nf < 4; nf++)
        #pragma unroll
        for (int kh = 0; kh < 2; kh++)
          acc[2+i][nf] = __builtin_amdgcn_mfma_f32_16x16x32_bf16(afr[i][kh], bfr[nf][kh], acc[2+i][nf], 0, 0, 0);
    __builtin_amdgcn_s_setprio(0);
    __builtin_amdgcn_s_barrier();
    __builtin_amdgcn_sched_barrier(0);

    // ---- phase 2
    gload16(Ag + (size_t)(128 + sr0    )*rK + kn, &sa[(128 + sr0    )*64]);
    gload16(Ag + (size_t)(128 + sr0 + 8)*rK + kn, &sa[(128 + sr0 + 8)*64]);
    #pragma unroll
    for (int i = 0; i < 2; i++)
      #pragma unroll
      for (int kh = 0; kh < 2; kh++)
        afr[i][kh] = *(const bf16x8*)&la[(wm*16 + (4+i)*32 + lrw)*64 + ((kh*32 + quad*8) ^ swr)];
    __builtin_amdgcn_s_barrier();
    __builtin_amdgcn_sched_barrier(0);
    __builtin_amdgcn_s_setprio(1);
    #pragma unroll
    for (int i = 0; i < 2; i++)
      #pragma unroll
      for (int nf = 0; nf < 4; nf++)
        #pragma unroll
        for (int kh = 0; kh < 2; kh++)
          acc[4+i][nf] = __builtin_amdgcn_mfma_f32_16x16x32_bf16(afr[i][kh], bfr[nf][kh], acc[4+i][nf], 0, 0, 0);
    __builtin_amdgcn_s_setprio(0);
    __builtin_amdgcn_s_barrier();
    __builtin_amdgcn_sched_barrier(0);

    // ---- phase 3
    #pragma unroll
    for (int i = 0; i < 2; i++)
      #pragma unroll
      for (int kh = 0; kh < 2; kh++)
        afr[i][kh] = *(const bf16x8*)&la[(wm*16 + (6+i)*32 + lrw)*64 + ((kh*32 + quad*8) ^ swr)];
    asm volatile("s_waitcnt vmcnt(2)" ::: "memory");
    __builtin_amdgcn_s_barrier();
    __builtin_amdgcn_sched_barrier(0);
    __builtin_amdgcn_s_setprio(1);
    #pragma unroll
    for (int i = 0; i < 2; i++)
      #pragma unroll
      for (int nf = 0; nf < 4; nf++)
        #pragma unroll
        for (int kh = 0; kh < 2; kh++)
          acc[6+i][nf] = __builtin_amdgcn_mfma_f32_16x16x32_bf16(afr[i][kh], bfr[nf][kh], acc[6+i][nf], 0, 0, 0);
    __builtin_amdgcn_s_setprio(0);
    __builtin_amdgcn_s_barrier();
    __builtin_amdgcn_sched_barrier(0);
  }

  asm volatile("s_waitcnt vmcnt(0)" ::: "memory");

  #pragma unroll
  for (int mf = 0; mf < 8; mf++){
    const int orow0 = bM + wm*16 + mf*32 + quad*4;
    #pragma unroll
    for (int nf = 0; nf < 4; nf++){
      const int ocol = bN + wn*16 + nf*64 + lrw;
      #pragma unroll
      for (int r = 0; r < 4; r++){
        size_t idx = (size_t)(orow0 + r)*N + ocol;
        if constexpr (sizeof(TC) == 4) C[idx] = acc[mf][nf][r];
        else                           C[idx] = f2b(acc[mf][nf][r]);
      }
    }
  }
}

// ---------------- m97-structure bf16 GEMM (kept for N=512 kvg) --------------------------
template<typename TC>
__global__ __launch_bounds__(256) void gemm_bf16(const u16* __restrict__ A,
    const u16* __restrict__ Bt, TC* __restrict__ C, int M, int N, int K)
{
  __shared__ u16 As[128*32];
  __shared__ u16 Bs[128*32];
  const int tid  = threadIdx.x;
  const int bM   = blockIdx.y * 128;
  const int bN   = blockIdx.x * 128;
  const int lane = tid & 63;
  const int w    = tid >> 6;
  const int wm   = w >> 1, wn = w & 1;
  const int lrow = lane & 15, quad = lane >> 4;
  const int srow = lane >> 2, skc = (lane & 3) * 8;

  const u16* Ab = &A [(size_t)(bM + w*32 + srow)*K + skc];
  const u16* Bb = &Bt[(size_t)(bN + w*32 + srow)*K + skc];
  const size_t row16 = (size_t)16 * K;

  f32x4 acc[4][4];
  #pragma unroll
  for (int i = 0; i < 4; i++)
    #pragma unroll
    for (int j = 0; j < 4; j++)
      #pragma unroll
      for (int r = 0; r < 4; r++) acc[i][j][r] = 0.f;

  for (int k0 = 0; k0 < K; k0 += 32){
    gload16(Ab + k0,         &As[(w*32     )*32]);
    gload16(Ab + k0 + row16, &As[(w*32 + 16)*32]);
    gload16(Bb + k0,         &Bs[(w*32     )*32]);
    gload16(Bb + k0 + row16, &Bs[(w*32 + 16)*32]);
    __syncthreads();

    bf16x8 af[4], bfv[4];
    #pragma unroll
    for (int mf = 0; mf < 4; mf++)
      af[mf] = *(const bf16x8*)&As[(wm*64 + mf*16 + lrow)*32 + quad*8];
    #pragma unroll
    for (int nf = 0; nf < 4; nf++)
      bfv[nf] = *(const bf16x8*)&Bs[(wn*64 + nf*16 + lrow)*32 + quad*8];
    #pragma unroll
    for (int mf = 0; mf < 4; mf++)
      #pragma unroll
      for (int nf = 0; nf < 4; nf++)
        acc[mf][nf] = __builtin_amdgcn_mfma_f32_16x16x32_bf16(af[mf], bfv[nf], acc[mf][nf], 0, 0, 0);
    __syncthreads();
  }
  #pragma unroll
  for (int mf = 0; mf < 4; mf++){
    #pragma unroll
    for (int nf = 0; nf < 4; nf++){
      int gcol = bN + wn*64 + nf*16 + lrow;
      #pragma unroll
      for (int r = 0; r < 4; r++){
        int grow = bM + wm*64 + mf*16 + quad*4 + r;
        size_t idx = (size_t)grow*N + gcol;
        if constexpr (sizeof(TC) == 4) C[idx] = acc[mf][nf][r];
        else                           C[idx] = f2b(acc[mf][nf][r]);
      }
    }
  }
}

// ---------------- fallback mixed GEMM (harness-verified R0 path) ------------------------
template<typename TA, typename TC>
__global__ __launch_bounds__(256) void gemm_any(const TA* __restrict__ A,
    const float* __restrict__ Bw, TC* __restrict__ C, int M, int N, int K)
{
  __shared__ u16 As[128*40];
  __shared__ u16 Bs[128*40];
  const int tid  = threadIdx.x;
  const int bM   = blockIdx.y * 128;
  const int bN   = blockIdx.x * 128;
  const int lane = tid & 63;
  const int wid  = tid >> 6;
  const int wm   = wid >> 1, wn = wid & 1;
  const int lrow = lane & 15, quad = lane >> 4;

  f32x4 acc[4][4];
  #pragma unroll
  for (int i = 0; i < 4; i++)
    #pragma unroll
    for (int j = 0; j < 4; j++)
      #pragma unroll
      for (int r = 0; r < 4; r++) acc[i][j][r] = 0.f;

  for (int k0 = 0; k0 < K; k0 += 32){
    #pragma unroll
    for (int i = 0; i < 4; i++){
      int c = tid + i*256;
      int row = c >> 3, kc = (c & 7) * 4;
      u16 tmp[4];
      if constexpr (sizeof(TA) == 4){
        float4 v = *(const float4*)&A[(size_t)(bM + row)*K + k0 + kc];
        tmp[0] = f2b(v.x); tmp[1] = f2b(v.y); tmp[2] = f2b(v.z); tmp[3] = f2b(v.w);
      } else {
        *(uint2*)tmp = *(const uint2*)&A[(size_t)(bM + row)*K + k0 + kc];
      }
      *(uint2*)&As[row*40 + kc] = *(uint2*)tmp;
    }
    #pragma unroll
    for (int i = 0; i < 4; i++){
      int c = tid + i*256;
      int kr = c >> 5, nc = (c & 31) * 4;
      float4 v = *(const float4*)&Bw[(size_t)(k0 + kr)*N + bN + nc];
      Bs[(nc+0)*40 + kr] = f2b(v.x);
      Bs[(nc+1)*40 + kr] = f2b(v.y);
      Bs[(nc+2)*40 + kr] = f2b(v.z);
      Bs[(nc+3)*40 + kr] = f2b(v.w);
    }
    __syncthreads();
    bf16x8 af[4], bfv[4];
    #pragma unroll
    for (int mf = 0; mf < 4; mf++)
      af[mf] = *(const bf16x8*)&As[(wm*64 + mf*16 + lrow)*40 + quad*8];
    #pragma unroll
    for (int nf = 0; nf < 4; nf++)
      bfv[nf] = *(const bf16x8*)&Bs[(wn*64 + nf*16 + lrow)*40 + quad*8];
    #pragma unroll
    for (int mf = 0; mf < 4; mf++)
      #pragma unroll
      for (int nf = 0; nf < 4; nf++)
        acc[mf][nf] = __builtin_amdgcn_mfma_f32_16x16x32_bf16(af[mf], bfv[nf], acc[mf][nf], 0, 0, 0);
    __syncthreads();
  }
  #pragma unroll
  for (int mf = 0; mf < 4; mf++){
    #pragma unroll
    for (int nf = 0; nf < 4; nf++){
      int gcol = bN + wn*64 + nf*16 + lrow;
      #pragma unroll
      for (int r = 0; r < 4; r++){
        int grow = bM + wm*64 + mf*16 + quad*4 + r;
        size_t idx = (size_t)grow*N + gcol;
        if constexpr (sizeof(TC) == 4) C[idx] = acc[mf][nf][r];
        else                           C[idx] = f2b(acc[mf][nf][r]);
      }
    }
  }
}

// ---------------- overlapped pooling + k RoPE; V written TRANSPOSED vT[b][d][w] ---------
__global__ void pool_rope_k(const u16* __restrict__ kv, const u16* __restrict__ gate,
                            const float* __restrict__ ape, u16* __restrict__ krot,
                            u16* __restrict__ vT, int str){
  const int d = threadIdx.x;   // 0..127
  const int w = blockIdx.x;    // 0..1023
  const int b = blockIdx.y;
  __shared__ float sh[HD];
  const bool hasprev = (w > 0);
  float gc[4], vc[4], gp[4], vp[4];
  float m = NEG_BIG;
  #pragma unroll
  for (int r = 0; r < 4; r++){
    size_t t = (size_t)(b*S_LEN + w*4 + r)*str;
    vc[r] = b2f(kv[t + 128 + d]);
    gc[r] = b2f(gate[t + 128 + d]) + ape[r*256 + 128 + d];
    m = fmaxf(m, gc[r]);
  }
  if (hasprev){
    #pragma unroll
    for (int r = 0; r < 4; r++){
      size_t t = (size_t)(b*S_LEN + (w-1)*4 + r)*str;
      vp[r] = b2f(kv[t + d]);
      gp[r] = b2f(gate[t + d]) + ape[r*256 + d];
      m = fmaxf(m, gp[r]);
    }
  }
  float s = 0.f, acc = 0.f;
  #pragma unroll
  for (int r = 0; r < 4; r++){
    float e = __expf(gc[r] - m); s += e; acc += e*vc[r];
  }
  if (hasprev){
    #pragma unroll
    for (int r = 0; r < 4; r++){
      float e = __expf(gp[r] - m); s += e; acc += e*vp[r];
    }
  }
  float pooled = acc / s;
  sh[d] = pooled;
  __syncthreads();
  float kr = pooled;
  if (d >= 64){
    int i = (d - 64) >> 1;
    float freq = expf(-(float)i * (LN10000 / 32.f));
    float ang = (float)(4*w) * freq;
    float sn, cs;
    sincosf(ang, &sn, &cs);
    if ((d & 1) == 0) kr = sh[d]*cs - sh[d+1]*sn;
    else              kr = sh[d-1]*sn + sh[d]*cs;
  }
  krot[(size_t)(b*NW + w)*HD + d] = f2b(kr);
  vT[(size_t)(b*HD + d)*NW + w]   = f2b(pooled);   // transposed for attn PV staging
}

// ---------------- MFMA flash attention: T14 prefetch + fused Q-RoPE ---------------------
// Structure as R5 (verified): 4 waves x 32 q-rows (2 groups of 16), swapped-operand MFMAs,
// register softmax, per-wave P strip. NEW: (1) K/V for chunk ch+1 prefetched into regs
// BEFORE the compute phase and written to LDS after the end barrier (T14: global-load
// latency hides under QK+softmax+PV); (2) partial interleaved RoPE applied to Q at load
// (one block owns each (b,q,h) slice; f32 rotate of bf16 inputs + f2b = bit-identical to
// the standalone rope_q + reload). rope_q kernel deleted.
#define AQT 128
#define AKT 64
#define AKSTR 136
#define AVSTR 72
#define APSTR 72
#define ATT_SCALE 0.088388347648318447f

__global__ __launch_bounds__(256, 2) void attn_kernel(
    const u16* __restrict__ qbuf, const u16* __restrict__ krot,
    const u16* __restrict__ vT, const float* __restrict__ sinks,
    u16* __restrict__ attnbuf)
{
  __shared__ u16 Ks[AKT*AKSTR];
  __shared__ u16 Vt[HD*AVSTR];
  __shared__ u16 Pq[AQT*APSTR];

  const int tid  = threadIdx.x;
  const int q0   = (int)(gridDim.x - 1 - blockIdx.x) * AQT;
  const int h    = blockIdx.y;
  const int b    = blockIdx.z;
  const int lane = tid & 63;
  const int wq   = tid >> 6;
  const int lrw  = lane & 15;
  const int quad = lane >> 4;
  const int qg0  = q0 + wq*32 + lrw;

  // Q fragments in registers, fused partial interleaved RoPE on d in [64,128)
  bf16x8 qf[2][4];
  #pragma unroll
  for (int g = 0; g < 2; g++){
    const u16* qrow = &qbuf[(size_t)(b*S_LEN + qg0 + g*16)*HID + h*HD];
    qf[g][0] = *(const bf16x8*)&qrow[0*32 + quad*8];
    qf[g][1] = *(const bf16x8*)&qrow[1*32 + quad*8];
    const float pos = (float)(qg0 + g*16);
    #pragma unroll
    for (int d0 = 2; d0 < 4; d0++){
      u16 raw[8];
      *(uint4*)raw = *(const uint4*)&qrow[d0*32 + quad*8];
      u16 outv[8];
      #pragma unroll
      for (int pr = 0; pr < 4; pr++){
        int i = (d0 - 2)*16 + quad*4 + pr;       // rope pair index 0..31
        float fr = expf(-(float)i * (LN10000/32.f));
        float sn, cs;
        sincosf(pos * fr, &sn, &cs);
        float a  = b2f(raw[2*pr]);
        float bb = b2f(raw[2*pr + 1]);
        outv[2*pr]     = f2b(a*cs - bb*sn);
        outv[2*pr + 1] = f2b(a*sn + bb*cs);
      }
      qf[g][d0] = *(bf16x8*)outv;
    }
  }

  float m_run[2] = {NEG_BIG, NEG_BIG};
  float l_run[2] = {0.f, 0.f};
  f32x4 accO[2][8];
  #pragma unroll
  for (int g = 0; g < 2; g++)
    #pragma unroll
    for (int ds = 0; ds < 8; ds++)
      #pragma unroll
      for (int r = 0; r < 4; r++) accO[g][ds][r] = 0.f;

  const int kmax_tile = (q0 + AQT - 1 - 3) >> 2;
  int nchunk = (kmax_tile >> 6) + 1;
  if (nchunk > NW/AKT) nchunk = NW/AKT;

  // stage chunk 0 (reg path; no barrier needed before first writes)
  #pragma unroll
  for (int i = 0; i < 4; i++){
    int c = tid + i*256;
    uint4 k0v = *(const uint4*)&krot[(size_t)(b*NW + (c >> 4))*HD + (c & 15)*8];
    uint4 v0v = *(const uint4*)&vT[(size_t)(b*HD + (c >> 3))*NW + (c & 7)*8];
    *(uint4*)&Ks[(c >> 4)*AKSTR + (c & 15)*8] = k0v;
    *(uint4*)&Vt[(c >> 3)*AVSTR + (c & 7)*8]  = v0v;
  }

  for (int ch = 0; ch < nchunk; ch++){
    const int kc0 = ch * AKT;
    __syncthreads();   // staged LDS (chunk ch) visible to all waves

    // T14: issue chunk ch+1 loads now; latency hides under the compute below
    const bool pf = (ch + 1 < nchunk);     // block-uniform
    uint4 krg[4], vrg[4];
    if (pf){
      const int kn = kc0 + AKT;
      #pragma unroll
      for (int i = 0; i < 4; i++){
        int c = tid + i*256;
        krg[i] = *(const uint4*)&krot[(size_t)(b*NW + kn + (c >> 4))*HD + (c & 15)*8];
        vrg[i] = *(const uint4*)&vT[(size_t)(b*HD + (c >> 3))*NW + kn + (c & 7)*8];
      }
    }

    f32x4 accS[2][4];
    #pragma unroll
    for (int g = 0; g < 2; g++)
      #pragma unroll
      for (int ks = 0; ks < 4; ks++)
        #pragma unroll
        for (int r = 0; r < 4; r++) accS[g][ks][r] = 0.f;
    #pragma unroll
    for (int d0 = 0; d0 < 4; d0++){
      #pragma unroll
      for (int ks = 0; ks < 4; ks++){
        bf16x8 kf = *(const bf16x8*)&Ks[(ks*16 + lrw)*AKSTR + d0*32 + quad*8];
        accS[0][ks] = __builtin_amdgcn_mfma_f32_16x16x32_bf16(kf, qf[0][d0], accS[0][ks], 0, 0, 0);
        accS[1][ks] = __builtin_amdgcn_mfma_f32_16x16x32_bf16(kf, qf[1][d0], accS[1][ks], 0, 0, 0);
      }
    }

    float alpha[2];
    #pragma unroll
    for (int g = 0; g < 2; g++){
      const int qg = qg0 + g*16;
      float p[16];
      float lmax = NEG_BIG;
      #pragma unroll
      for (int ks = 0; ks < 4; ks++)
        #pragma unroll
        for (int r = 0; r < 4; r++){
          int kg = kc0 + ks*16 + quad*4 + r;
          float s = (qg >= 4*kg + 3) ? accS[g][ks][r]*ATT_SCALE : NEG_BIG;
          p[ks*4 + r] = s;
          lmax = fmaxf(lmax, s);
        }
      lmax = fmaxf(lmax, __shfl_xor(lmax, 16));
      lmax = fmaxf(lmax, __shfl_xor(lmax, 32));
      float mnew = fmaxf(m_run[g], lmax);
      alpha[g] = __expf(m_run[g] - mnew);
      m_run[g] = mnew;
      float ls = 0.f;
      #pragma unroll
      for (int i = 0; i < 16; i++){
        float e = __expf(p[i] - mnew);
        p[i] = e; ls += e;
      }
      ls += __shfl_xor(ls, 16);
      ls += __shfl_xor(ls, 32);
      l_run[g] = l_run[g]*alpha[g] + ls;
      #pragma unroll
      for (int ks = 0; ks < 4; ks++){
        u16 pb[4];
        #pragma unroll
        for (int r = 0; r < 4; r++) pb[r] = f2b(p[ks*4 + r]);
        *(uint2*)&Pq[(wq*32 + g*16 + lrw)*APSTR + ks*16 + quad*4] = *(uint2*)pb;
      }
    }

    #pragma unroll
    for (int g = 0; g < 2; g++)
      #pragma unroll
      for (int ds = 0; ds < 8; ds++)
        #pragma unroll
        for (int r = 0; r < 4; r++) accO[g][ds][r] *= alpha[g];

    #pragma unroll
    for (int kks = 0; kks < 2; kks++){
      bf16x8 pf0 = *(const bf16x8*)&Pq[(wq*32      + lrw)*APSTR + kks*32 + quad*8];
      bf16x8 pf1 = *(const bf16x8*)&Pq[(wq*32 + 16 + lrw)*APSTR + kks*32 + quad*8];
      #pragma unroll
      for (int ds = 0; ds < 8; ds++){
        bf16x8 av = *(const bf16x8*)&Vt[(ds*16 + lrw)*AVSTR + kks*32 + quad*8];
        accO[0][ds] = __builtin_amdgcn_mfma_f32_16x16x32_bf16(av, pf0, accO[0][ds], 0, 0, 0);
        accO[1][ds] = __builtin_amdgcn_mfma_f32_16x16x32_bf16(av, pf1, accO[1][ds], 0, 0, 0);
      }
    }
    __syncthreads();   // all LDS reads of chunk ch done

    if (pf){           // write prefetched chunk ch+1 (compiler inserts vmcnt here)
      #pragma unroll
      for (int i = 0; i < 4; i++){
        int c = tid + i*256;
        *(uint4*)&Ks[(c >> 4)*AKSTR + (c & 15)*8] = krg[i];
        *(uint4*)&Vt[(c >> 3)*AVSTR + (c & 7)*8]  = vrg[i];
      }
    }
  }

  const float snk = sinks[h];
  #pragma unroll
  for (int g = 0; g < 2; g++){
    float mf = fmaxf(m_run[g], snk);
    float em = __expf(m_run[g] - mf);
    float sc = em / (l_run[g]*em + __expf(snk - mf));
    size_t o = (size_t)(b*S_LEN + qg0 + g*16)*HID + h*HD;
    #pragma unroll
    for (int ds = 0; ds < 8; ds++){
      u16 ob[4];
      #pragma unroll
      for (int r = 0; r < 4; r++) ob[r] = f2b(accO[g][ds][r] * sc);
      *(uint2*)&attnbuf[o + ds*16 + quad*4] = *(uint2*)ob;
    }
  }
}

// ---------------------------------------------------------------------------------------
extern "C" void kernel_launch(void* const* d_in, const int* in_sizes, int n_in,
                              void* d_out, int out_size, void* d_ws, size_t ws_size,
                              hipStream_t stream)
{
  const float* hidden = (const float*)d_in[0];
  const float* wq     = (const float*)d_in[1];
  const float* wkv    = (const float*)d_in[2];
  const float* wgate  = (const float*)d_in[3];
  const float* ape    = (const float*)d_in[4];
  const float* sinks  = (const float*)d_in[5];
  const float* wo     = (const float*)d_in[6];

  const size_t NEED = ((size_t)TOK*HID*2 + (size_t)TOK*512 + (size_t)4*NW*HD
                     + (size_t)HID*HID + (size_t)512*HID) * sizeof(u16); // 87.0 MB

  if (ws_size >= NEED){
    u16* hid_bf = (u16*)d_ws;                         // TOK*HID       (also attnbuf)
    u16* qbuf   = hid_bf + (size_t)TOK*HID;           // TOK*HID
    u16* kvg    = qbuf   + (size_t)TOK*HID;           // TOK*512       (also woT)
    u16* krot   = kvg    + (size_t)TOK*512;           // 2*NW*HD
    u16* vTb    = krot   + (size_t)2*NW*HD;           // 2*HD*NW (transposed V)
    u16* wqT    = vTb    + (size_t)2*NW*HD;           // 2048*2048
    u16* wkvgT  = wqT    + (size_t)HID*HID;           // 512*2048
    u16* attnbuf = hid_bf;
    u16* woT     = kvg;

    cvt_bf16<<<(TOK*HID/8)/256, 256, 0, stream>>>(hidden, hid_bf);
    transpose_w<<<dim3(HID/32, HID/32), 256, 0, stream>>>(wq, wqT, HID, HID);
    transpose_w<<<dim3(256/32, HID/32), 256, 0, stream>>>(wkv,   wkvgT,            HID, 256);
    transpose_w<<<dim3(256/32, HID/32), 256, 0, stream>>>(wgate, wkvgT + (size_t)256*HID, HID, 256);
    gemm256<u16><<<dim3((TOK/256)*(HID/256)), 512, 0, stream>>>(hid_bf, wqT, qbuf, TOK, HID, HID);
    gemm_bf16<u16><<<dim3(512/128, TOK/128), 256, 0, stream>>>(hid_bf, wkvgT, kvg,  TOK, 512, HID);
    pool_rope_k<<<dim3(NW, 2), 128, 0, stream>>>(kvg, kvg + 256, ape, krot, vTb, 512);
    attn_kernel<<<dim3(S_LEN/AQT, NHEAD, 2), 256, 0, stream>>>(qbuf, krot, vTb, sinks, attnbuf);
    transpose_w<<<dim3(HID/32, HID/32), 256, 0, stream>>>(wo, woT, HID, HID);   // kvg dead
    gemm256<float><<<dim3((TOK/256)*(HID/256)), 512, 0, stream>>>(attnbuf, woT, (float*)d_out, TOK, HID, HID);
  } else {
    // fallback: R0 verified GEMM path + attn (RoPE now fused in attn; no rope_q)
    u16* qbuf    = (u16*)d_ws;
    u16* kvbuf   = qbuf    + (size_t)TOK*HID;
    u16* gatebuf = kvbuf   + (size_t)TOK*256;
    u16* krot    = gatebuf + (size_t)TOK*256;
    u16* vTb     = krot    + (size_t)2*NW*HD;
    u16* attnbuf = vTb     + (size_t)2*NW*HD;

    gemm_any<float,u16><<<dim3(HID/128, TOK/128), 256, 0, stream>>>(hidden, wq,    qbuf,    TOK, HID, HID);
    gemm_any<float,u16><<<dim3(256/128, TOK/128), 256, 0, stream>>>(hidden, wkv,   kvbuf,   TOK, 256, HID);
    gemm_any<float,u16><<<dim3(256/128, TOK/128), 256, 0, stream>>>(hidden, wgate, gatebuf, TOK, 256, HID);
    pool_rope_k<<<dim3(NW, 2), 128, 0, stream>>>(kvbuf, gatebuf, ape, krot, vTb, 256);
    attn_kernel<<<dim3(S_LEN/AQT, NHEAD, 2), 256, 0, stream>>>(qbuf, krot, vTb, sinks, attnbuf);
    gemm_any<u16,float><<<dim3(HID/128, TOK/128), 256, 0, stream>>>(attnbuf, wo, (float*)d_out, TOK, HID, HID);
  }
}

// Round 8
// 500.274 us; speedup vs baseline: 1.1234x; 1.1234x over previous
//
#include <hip/hip_runtime.h>
#include <math.h>

typedef unsigned short u16;
typedef unsigned int   u32;
typedef __bf16 bf16x8 __attribute__((ext_vector_type(8)));
typedef float  f32x4  __attribute__((ext_vector_type(4)));

#define S_LEN 4096
#define HID   2048
#define NHEAD 16
#define HD    128
#define NW    1024
#define TOK   8192
#define LN10000 9.2103403719761836f
#define NEG_BIG (-1e30f)

__device__ __forceinline__ float b2f(u16 u){
  union { u32 i; float f; } v; v.i = ((u32)u) << 16; return v.f;
}
__device__ __forceinline__ u16 f2b(float f){
  union { float f; u32 i; } v; v.f = f;
  return (u16)((v.i + 0x7FFFu + ((v.i >> 16) & 1u)) >> 16);
}

// ---------------- one-time f32 -> bf16 convert (hidden), 8 elems/thread -----------------
__global__ __launch_bounds__(256) void cvt_bf16(const float* __restrict__ in,
                                                u16* __restrict__ out){
  size_t i = (size_t)blockIdx.x*256 + threadIdx.x;
  float4 a = ((const float4*)in)[2*i];
  float4 b = ((const float4*)in)[2*i+1];
  u16 t[8];
  t[0]=f2b(a.x); t[1]=f2b(a.y); t[2]=f2b(a.z); t[3]=f2b(a.w);
  t[4]=f2b(b.x); t[5]=f2b(b.y); t[6]=f2b(b.z); t[7]=f2b(b.w);
  *(uint4*)&out[i*8] = *(uint4*)t;
}

// ---------------- one-time weight transpose+convert: f32[K][N] -> bf16[N][K] ------------
__global__ __launch_bounds__(256) void transpose_w(const float* __restrict__ in,
    u16* __restrict__ out, int K, int N){
  __shared__ float t[32][33];
  const int n0 = blockIdx.x*32, k0 = blockIdx.y*32;
  const int c = threadIdx.x & 31, r8 = threadIdx.x >> 5;
  #pragma unroll
  for (int i = 0; i < 4; i++)
    t[r8 + i*8][c] = in[(size_t)(k0 + r8 + i*8)*N + n0 + c];
  __syncthreads();
  #pragma unroll
  for (int i = 0; i < 4; i++)
    out[(size_t)(n0 + r8 + i*8)*K + k0 + c] = f2b(t[c][r8 + i*8]);
}

typedef __attribute__((address_space(3))) u16 as3_u16;
typedef __attribute__((address_space(1))) const u16 as1_u16;
__device__ __forceinline__ void gload16(const u16* g, u16* l){
  __builtin_amdgcn_global_load_lds((as1_u16*)g, (as3_u16*)l, 16, 0, 0);
}

// ---------------- 256x256 8-phase GEMM (T2+T3+T4+T5): C = A(M,K) @ Bt(N,K)^T ------------
// Unchanged from R5/R6 (harness-verified). BK=64, 8 waves, 128KB LDS dbuf, counted vmcnt,
// both-sides XOR swizzle, setprio around MFMA clusters.
template<typename TC>
__global__ __launch_bounds__(512, 1) void gemm256(const u16* __restrict__ A,
    const u16* __restrict__ Bt, TC* __restrict__ C, int M, int N, int K)
{
  __shared__ __align__(16) u16 LA[2][256*64];
  __shared__ __align__(16) u16 LB[2][256*64];
  const int tid  = threadIdx.x;
  const int lane = tid & 63;
  const int w    = tid >> 6;        // 0..7
  const int wm   = w & 1;
  const int wn   = w >> 1;          // 0..3
  const int lrw  = lane & 15;
  const int quad = lane >> 4;
  const int NB   = N >> 8;
  const int nwg  = gridDim.x;
  const int bid  = blockIdx.x;
  const int swz  = (bid & 7) * (nwg >> 3) + (bid >> 3);
  const int bN   = (swz % NB) << 8;
  const int bM   = (swz / NB) << 8;

  const int rlo = lane >> 3;
  const int csw = ((lane & 7) ^ rlo) << 3;
  const int sr0 = w * 16;
  const int swr = (lrw & 7) << 3;
  const u16* Ag = A  + (size_t)bM * K + (size_t)rlo * K + csw;
  const u16* Bg = Bt + (size_t)bN * K + (size_t)rlo * K + csw;
  const size_t rK = (size_t)K;

  f32x4 acc[8][4];
  #pragma unroll
  for (int i = 0; i < 8; i++)
    #pragma unroll
    for (int j = 0; j < 4; j++)
      #pragma unroll
      for (int r = 0; r < 4; r++) acc[i][j][r] = 0.f;

  const int NT = K >> 6;

  gload16(Ag + (size_t)(  0 + sr0    )*rK, &LA[0][(  0 + sr0    )*64]);
  gload16(Ag + (size_t)(  0 + sr0 + 8)*rK, &LA[0][(  0 + sr0 + 8)*64]);
  gload16(Bg + (size_t)(  0 + sr0    )*rK, &LB[0][(  0 + sr0    )*64]);
  gload16(Bg + (size_t)(  0 + sr0 + 8)*rK, &LB[0][(  0 + sr0 + 8)*64]);
  gload16(Bg + (size_t)(128 + sr0    )*rK, &LB[0][(128 + sr0    )*64]);
  gload16(Bg + (size_t)(128 + sr0 + 8)*rK, &LB[0][(128 + sr0 + 8)*64]);
  gload16(Ag + (size_t)(128 + sr0    )*rK, &LA[0][(128 + sr0    )*64]);
  gload16(Ag + (size_t)(128 + sr0 + 8)*rK, &LA[0][(128 + sr0 + 8)*64]);
  asm volatile("s_waitcnt vmcnt(2)" ::: "memory");
  __builtin_amdgcn_s_barrier();
  __builtin_amdgcn_sched_barrier(0);

  for (int t = 0; t < NT; ++t){
    const int cur = t & 1, nxt = cur ^ 1;
    const int kn  = ((t + 1) & (NT - 1)) << 6;
    const u16* la = &LA[cur][0];
    const u16* lb = &LB[cur][0];
    u16* sa = &LA[nxt][0];
    u16* sb = &LB[nxt][0];

    bf16x8 bfr[4][2], afr[2][2];

    // ---- phase 0
    gload16(Ag + (size_t)(  0 + sr0    )*rK + kn, &sa[(  0 + sr0    )*64]);
    gload16(Ag + (size_t)(  0 + sr0 + 8)*rK + kn, &sa[(  0 + sr0 + 8)*64]);
    gload16(Bg + (size_t)(  0 + sr0    )*rK + kn, &sb[(  0 + sr0    )*64]);
    gload16(Bg + (size_t)(  0 + sr0 + 8)*rK + kn, &sb[(  0 + sr0 + 8)*64]);
    #pragma unroll
    for (int nf = 0; nf < 4; nf++)
      #pragma unroll
      for (int kh = 0; kh < 2; kh++)
        bfr[nf][kh] = *(const bf16x8*)&lb[(wn*16 + nf*64 + lrw)*64 + ((kh*32 + quad*8) ^ swr)];
    #pragma unroll
    for (int i = 0; i < 2; i++)
      #pragma unroll
      for (int kh = 0; kh < 2; kh++)
        afr[i][kh] = *(const bf16x8*)&la[(wm*16 + (0+i)*32 + lrw)*64 + ((kh*32 + quad*8) ^ swr)];
    __builtin_amdgcn_s_barrier();
    __builtin_amdgcn_sched_barrier(0);
    __builtin_amdgcn_s_setprio(1);
    #pragma unroll
    for (int i = 0; i < 2; i++)
      #pragma unroll
      for (int nf = 0; nf < 4; nf++)
        #pragma unroll
        for (int kh = 0; kh < 2; kh++)
          acc[0+i][nf] = __builtin_amdgcn_mfma_f32_16x16x32_bf16(afr[i][kh], bfr[nf][kh], acc[0+i][nf], 0, 0, 0);
    __builtin_amdgcn_s_setprio(0);
    __builtin_amdgcn_s_barrier();
    __builtin_amdgcn_sched_barrier(0);

    // ---- phase 1
    gload16(Bg + (size_t)(128 + sr0    )*rK + kn, &sb[(128 + sr0    )*64]);
    gload16(Bg + (size_t)(128 + sr0 + 8)*rK + kn, &sb[(128 + sr0 + 8)*64]);
    #pragma unroll
    for (int i = 0; i < 2; i++)
      #pragma unroll
      for (int kh = 0; kh < 2; kh++)
        afr[i][kh] = *(const bf16x8*)&la[(wm*16 + (2+i)*32 + lrw)*64 + ((kh*32 + quad*8) ^ swr)];
    asm volatile("s_waitcnt vmcnt(6)" ::: "memory");
    __builtin_amdgcn_s_barrier();
    __builtin_amdgcn_sched_barrier(0);
    __builtin_amdgcn_s_setprio(1);
    #pragma unroll
    for (int i = 0; i < 2; i++)
      #pragma unroll
      for (int nf = 0; nf < 4; nf++)
        #pragma unroll
        for (int kh = 0; kh < 2; kh++)
          acc[2+i][nf] = __builtin_amdgcn_mfma_f32_16x16x32_bf16(afr[i][kh], bfr[nf][kh], acc[2+i][nf], 0, 0, 0);
    __builtin_amdgcn_s_setprio(0);
    __builtin_amdgcn_s_barrier();
    __builtin_amdgcn_sched_barrier(0);

    // ---- phase 2
    gload16(Ag + (size_t)(128 + sr0    )*rK + kn, &sa[(128 + sr0    )*64]);
    gload16(Ag + (size_t)(128 + sr0 + 8)*rK + kn, &sa[(128 + sr0 + 8)*64]);
    #pragma unroll
    for (int i = 0; i < 2; i++)
      #pragma unroll
      for (int kh = 0; kh < 2; kh++)
        afr[i][kh] = *(const bf16x8*)&la[(wm*16 + (4+i)*32 + lrw)*64 + ((kh*32 + quad*8) ^ swr)];
    __builtin_amdgcn_s_barrier();
    __builtin_amdgcn_sched_barrier(0);
    __builtin_amdgcn_s_setprio(1);
    #pragma unroll
    for (int i = 0; i < 2; i++)
      #pragma unroll
      for (int nf = 0; nf < 4; nf++)
        #pragma unroll
        for (int kh = 0; kh < 2; kh++)
          acc[4+i][nf] = __builtin_amdgcn_mfma_f32_16x16x32_bf16(afr[i][kh], bfr[nf][kh], acc[4+i][nf], 0, 0, 0);
    __builtin_amdgcn_s_setprio(0);
    __builtin_amdgcn_s_barrier();
    __builtin_amdgcn_sched_barrier(0);

    // ---- phase 3
    #pragma unroll
    for (int i = 0; i < 2; i++)
      #pragma unroll
      for (int kh = 0; kh < 2; kh++)
        afr[i][kh] = *(const bf16x8*)&la[(wm*16 + (6+i)*32 + lrw)*64 + ((kh*32 + quad*8) ^ swr)];
    asm volatile("s_waitcnt vmcnt(2)" ::: "memory");
    __builtin_amdgcn_s_barrier();
    __builtin_amdgcn_sched_barrier(0);
    __builtin_amdgcn_s_setprio(1);
    #pragma unroll
    for (int i = 0; i < 2; i++)
      #pragma unroll
      for (int nf = 0; nf < 4; nf++)
        #pragma unroll
        for (int kh = 0; kh < 2; kh++)
          acc[6+i][nf] = __builtin_amdgcn_mfma_f32_16x16x32_bf16(afr[i][kh], bfr[nf][kh], acc[6+i][nf], 0, 0, 0);
    __builtin_amdgcn_s_setprio(0);
    __builtin_amdgcn_s_barrier();
    __builtin_amdgcn_sched_barrier(0);
  }

  asm volatile("s_waitcnt vmcnt(0)" ::: "memory");

  #pragma unroll
  for (int mf = 0; mf < 8; mf++){
    const int orow0 = bM + wm*16 + mf*32 + quad*4;
    #pragma unroll
    for (int nf = 0; nf < 4; nf++){
      const int ocol = bN + wn*16 + nf*64 + lrw;
      #pragma unroll
      for (int r = 0; r < 4; r++){
        size_t idx = (size_t)(orow0 + r)*N + ocol;
        if constexpr (sizeof(TC) == 4) C[idx] = acc[mf][nf][r];
        else                           C[idx] = f2b(acc[mf][nf][r]);
      }
    }
  }
}

// ---------------- m97-structure bf16 GEMM (kept for N=512 kvg) --------------------------
template<typename TC>
__global__ __launch_bounds__(256) void gemm_bf16(const u16* __restrict__ A,
    const u16* __restrict__ Bt, TC* __restrict__ C, int M, int N, int K)
{
  __shared__ u16 As[128*32];
  __shared__ u16 Bs[128*32];
  const int tid  = threadIdx.x;
  const int bM   = blockIdx.y * 128;
  const int bN   = blockIdx.x * 128;
  const int lane = tid & 63;
  const int w    = tid >> 6;
  const int wm   = w >> 1, wn = w & 1;
  const int lrow = lane & 15, quad = lane >> 4;
  const int srow = lane >> 2, skc = (lane & 3) * 8;

  const u16* Ab = &A [(size_t)(bM + w*32 + srow)*K + skc];
  const u16* Bb = &Bt[(size_t)(bN + w*32 + srow)*K + skc];
  const size_t row16 = (size_t)16 * K;

  f32x4 acc[4][4];
  #pragma unroll
  for (int i = 0; i < 4; i++)
    #pragma unroll
    for (int j = 0; j < 4; j++)
      #pragma unroll
      for (int r = 0; r < 4; r++) acc[i][j][r] = 0.f;

  for (int k0 = 0; k0 < K; k0 += 32){
    gload16(Ab + k0,         &As[(w*32     )*32]);
    gload16(Ab + k0 + row16, &As[(w*32 + 16)*32]);
    gload16(Bb + k0,         &Bs[(w*32     )*32]);
    gload16(Bb + k0 + row16, &Bs[(w*32 + 16)*32]);
    __syncthreads();

    bf16x8 af[4], bfv[4];
    #pragma unroll
    for (int mf = 0; mf < 4; mf++)
      af[mf] = *(const bf16x8*)&As[(wm*64 + mf*16 + lrow)*32 + quad*8];
    #pragma unroll
    for (int nf = 0; nf < 4; nf++)
      bfv[nf] = *(const bf16x8*)&Bs[(wn*64 + nf*16 + lrow)*32 + quad*8];
    #pragma unroll
    for (int mf = 0; mf < 4; mf++)
      #pragma unroll
      for (int nf = 0; nf < 4; nf++)
        acc[mf][nf] = __builtin_amdgcn_mfma_f32_16x16x32_bf16(af[mf], bfv[nf], acc[mf][nf], 0, 0, 0);
    __syncthreads();
  }
  #pragma unroll
  for (int mf = 0; mf < 4; mf++){
    #pragma unroll
    for (int nf = 0; nf < 4; nf++){
      int gcol = bN + wn*64 + nf*16 + lrow;
      #pragma unroll
      for (int r = 0; r < 4; r++){
        int grow = bM + wm*64 + mf*16 + quad*4 + r;
        size_t idx = (size_t)grow*N + gcol;
        if constexpr (sizeof(TC) == 4) C[idx] = acc[mf][nf][r];
        else                           C[idx] = f2b(acc[mf][nf][r]);
      }
    }
  }
}

// ---------------- fallback mixed GEMM (harness-verified R0 path) ------------------------
template<typename TA, typename TC>
__global__ __launch_bounds__(256) void gemm_any(const TA* __restrict__ A,
    const float* __restrict__ Bw, TC* __restrict__ C, int M, int N, int K)
{
  __shared__ u16 As[128*40];
  __shared__ u16 Bs[128*40];
  const int tid  = threadIdx.x;
  const int bM   = blockIdx.y * 128;
  const int bN   = blockIdx.x * 128;
  const int lane = tid & 63;
  const int wid  = tid >> 6;
  const int wm   = wid >> 1, wn = wid & 1;
  const int lrow = lane & 15, quad = lane >> 4;

  f32x4 acc[4][4];
  #pragma unroll
  for (int i = 0; i < 4; i++)
    #pragma unroll
    for (int j = 0; j < 4; j++)
      #pragma unroll
      for (int r = 0; r < 4; r++) acc[i][j][r] = 0.f;

  for (int k0 = 0; k0 < K; k0 += 32){
    #pragma unroll
    for (int i = 0; i < 4; i++){
      int c = tid + i*256;
      int row = c >> 3, kc = (c & 7) * 4;
      u16 tmp[4];
      if constexpr (sizeof(TA) == 4){
        float4 v = *(const float4*)&A[(size_t)(bM + row)*K + k0 + kc];
        tmp[0] = f2b(v.x); tmp[1] = f2b(v.y); tmp[2] = f2b(v.z); tmp[3] = f2b(v.w);
      } else {
        *(uint2*)tmp = *(const uint2*)&A[(size_t)(bM + row)*K + k0 + kc];
      }
      *(uint2*)&As[row*40 + kc] = *(uint2*)tmp;
    }
    #pragma unroll
    for (int i = 0; i < 4; i++){
      int c = tid + i*256;
      int kr = c >> 5, nc = (c & 31) * 4;
      float4 v = *(const float4*)&Bw[(size_t)(k0 + kr)*N + bN + nc];
      Bs[(nc+0)*40 + kr] = f2b(v.x);
      Bs[(nc+1)*40 + kr] = f2b(v.y);
      Bs[(nc+2)*40 + kr] = f2b(v.z);
      Bs[(nc+3)*40 + kr] = f2b(v.w);
    }
    __syncthreads();
    bf16x8 af[4], bfv[4];
    #pragma unroll
    for (int mf = 0; mf < 4; mf++)
      af[mf] = *(const bf16x8*)&As[(wm*64 + mf*16 + lrow)*40 + quad*8];
    #pragma unroll
    for (int nf = 0; nf < 4; nf++)
      bfv[nf] = *(const bf16x8*)&Bs[(wn*64 + nf*16 + lrow)*40 + quad*8];
    #pragma unroll
    for (int mf = 0; mf < 4; mf++)
      #pragma unroll
      for (int nf = 0; nf < 4; nf++)
        acc[mf][nf] = __builtin_amdgcn_mfma_f32_16x16x32_bf16(af[mf], bfv[nf], acc[mf][nf], 0, 0, 0);
    __syncthreads();
  }
  #pragma unroll
  for (int mf = 0; mf < 4; mf++){
    #pragma unroll
    for (int nf = 0; nf < 4; nf++){
      int gcol = bN + wn*64 + nf*16 + lrow;
      #pragma unroll
      for (int r = 0; r < 4; r++){
        int grow = bM + wm*64 + mf*16 + quad*4 + r;
        size_t idx = (size_t)grow*N + gcol;
        if constexpr (sizeof(TC) == 4) C[idx] = acc[mf][nf][r];
        else                           C[idx] = f2b(acc[mf][nf][r]);
      }
    }
  }
}

// ---------------- overlapped pooling + k RoPE; V written TRANSPOSED vT[b][d][w] ---------
__global__ void pool_rope_k(const u16* __restrict__ kv, const u16* __restrict__ gate,
                            const float* __restrict__ ape, u16* __restrict__ krot,
                            u16* __restrict__ vT, int str){
  const int d = threadIdx.x;   // 0..127
  const int w = blockIdx.x;    // 0..1023
  const int b = blockIdx.y;
  __shared__ float sh[HD];
  const bool hasprev = (w > 0);
  float gc[4], vc[4], gp[4], vp[4];
  float m = NEG_BIG;
  #pragma unroll
  for (int r = 0; r < 4; r++){
    size_t t = (size_t)(b*S_LEN + w*4 + r)*str;
    vc[r] = b2f(kv[t + 128 + d]);
    gc[r] = b2f(gate[t + 128 + d]) + ape[r*256 + 128 + d];
    m = fmaxf(m, gc[r]);
  }
  if (hasprev){
    #pragma unroll
    for (int r = 0; r < 4; r++){
      size_t t = (size_t)(b*S_LEN + (w-1)*4 + r)*str;
      vp[r] = b2f(kv[t + d]);
      gp[r] = b2f(gate[t + d]) + ape[r*256 + d];
      m = fmaxf(m, gp[r]);
    }
  }
  float s = 0.f, acc = 0.f;
  #pragma unroll
  for (int r = 0; r < 4; r++){
    float e = __expf(gc[r] - m); s += e; acc += e*vc[r];
  }
  if (hasprev){
    #pragma unroll
    for (int r = 0; r < 4; r++){
      float e = __expf(gp[r] - m); s += e; acc += e*vp[r];
    }
  }
  float pooled = acc / s;
  sh[d] = pooled;
  __syncthreads();
  float kr = pooled;
  if (d >= 64){
    int i = (d - 64) >> 1;
    float freq = expf(-(float)i * (LN10000 / 32.f));
    float ang = (float)(4*w) * freq;
    float sn, cs;
    sincosf(ang, &sn, &cs);
    if ((d & 1) == 0) kr = sh[d]*cs - sh[d+1]*sn;
    else              kr = sh[d-1]*sn + sh[d]*cs;
  }
  krot[(size_t)(b*NW + w)*HD + d] = f2b(kr);
  vT[(size_t)(b*HD + d)*NW + w]   = f2b(pooled);   // transposed for attn PV staging
}

// ---------------- MFMA flash attention: R5 staging (verified) + fused Q-RoPE ------------
// Structure = R5 (verified 115us, no spill): direct uint4 LDS staging per chunk, 2
// barriers. Fused partial interleaved RoPE on Q at load (one block owns each (b,q,h)
// slice; f32 rotate + f2b = bit-identical to standalone rope_q + reload). The R6 T14
// reg-prefetch is REVERTED: +32 live VGPR across compute spilled to scratch
// (WRITE_SIZE 32->76MB) and cost +79us.
#define AQT 128
#define AKT 64
#define AKSTR 136
#define AVSTR 72
#define APSTR 72
#define ATT_SCALE 0.088388347648318447f

__global__ __launch_bounds__(256, 2) void attn_kernel(
    const u16* __restrict__ qbuf, const u16* __restrict__ krot,
    const u16* __restrict__ vT, const float* __restrict__ sinks,
    u16* __restrict__ attnbuf)
{
  __shared__ u16 Ks[AKT*AKSTR];
  __shared__ u16 Vt[HD*AVSTR];
  __shared__ u16 Pq[AQT*APSTR];

  const int tid  = threadIdx.x;
  const int q0   = (int)(gridDim.x - 1 - blockIdx.x) * AQT;
  const int h    = blockIdx.y;
  const int b    = blockIdx.z;
  const int lane = tid & 63;
  const int wq   = tid >> 6;
  const int lrw  = lane & 15;
  const int quad = lane >> 4;
  const int qg0  = q0 + wq*32 + lrw;

  // Q fragments in registers, fused partial interleaved RoPE on d in [64,128)
  bf16x8 qf[2][4];
  #pragma unroll
  for (int g = 0; g < 2; g++){
    const u16* qrow = &qbuf[(size_t)(b*S_LEN + qg0 + g*16)*HID + h*HD];
    qf[g][0] = *(const bf16x8*)&qrow[0*32 + quad*8];
    qf[g][1] = *(const bf16x8*)&qrow[1*32 + quad*8];
    const float pos = (float)(qg0 + g*16);
    #pragma unroll
    for (int d0 = 2; d0 < 4; d0++){
      u16 raw[8];
      *(uint4*)raw = *(const uint4*)&qrow[d0*32 + quad*8];
      u16 outv[8];
      #pragma unroll
      for (int pr = 0; pr < 4; pr++){
        int i = (d0 - 2)*16 + quad*4 + pr;       // rope pair index 0..31
        float fr = expf(-(float)i * (LN10000/32.f));
        float sn, cs;
        sincosf(pos * fr, &sn, &cs);
        float a  = b2f(raw[2*pr]);
        float bb = b2f(raw[2*pr + 1]);
        outv[2*pr]     = f2b(a*cs - bb*sn);
        outv[2*pr + 1] = f2b(a*sn + bb*cs);
      }
      qf[g][d0] = *(bf16x8*)outv;
    }
  }

  float m_run[2] = {NEG_BIG, NEG_BIG};
  float l_run[2] = {0.f, 0.f};
  f32x4 accO[2][8];
  #pragma unroll
  for (int g = 0; g < 2; g++)
    #pragma unroll
    for (int ds = 0; ds < 8; ds++)
      #pragma unroll
      for (int r = 0; r < 4; r++) accO[g][ds][r] = 0.f;

  const int kmax_tile = (q0 + AQT - 1 - 3) >> 2;
  int nchunk = (kmax_tile >> 6) + 1;
  if (nchunk > NW/AKT) nchunk = NW/AKT;

  for (int ch = 0; ch < nchunk; ch++){
    const int kc0 = ch * AKT;
    #pragma unroll
    for (int i = 0; i < 4; i++){
      int c = tid + i*256;
      int kl = c >> 4, cc = (c & 15) * 8;
      *(uint4*)&Ks[kl*AKSTR + cc] =
        *(const uint4*)&krot[(size_t)(b*NW + kc0 + kl)*HD + cc];
    }
    #pragma unroll
    for (int i = 0; i < 4; i++){
      int c = tid + i*256;
      int dv = c >> 3, cc = (c & 7) * 8;
      *(uint4*)&Vt[dv*AVSTR + cc] =
        *(const uint4*)&vT[(size_t)(b*HD + dv)*NW + kc0 + cc];
    }
    __syncthreads();

    f32x4 accS[2][4];
    #pragma unroll
    for (int g = 0; g < 2; g++)
      #pragma unroll
      for (int ks = 0; ks < 4; ks++)
        #pragma unroll
        for (int r = 0; r < 4; r++) accS[g][ks][r] = 0.f;
    #pragma unroll
    for (int d0 = 0; d0 < 4; d0++){
      #pragma unroll
      for (int ks = 0; ks < 4; ks++){
        bf16x8 kf = *(const bf16x8*)&Ks[(ks*16 + lrw)*AKSTR + d0*32 + quad*8];
        accS[0][ks] = __builtin_amdgcn_mfma_f32_16x16x32_bf16(kf, qf[0][d0], accS[0][ks], 0, 0, 0);
        accS[1][ks] = __builtin_amdgcn_mfma_f32_16x16x32_bf16(kf, qf[1][d0], accS[1][ks], 0, 0, 0);
      }
    }

    float alpha[2];
    #pragma unroll
    for (int g = 0; g < 2; g++){
      const int qg = qg0 + g*16;
      float p[16];
      float lmax = NEG_BIG;
      #pragma unroll
      for (int ks = 0; ks < 4; ks++)
        #pragma unroll
        for (int r = 0; r < 4; r++){
          int kg = kc0 + ks*16 + quad*4 + r;
          float s = (qg >= 4*kg + 3) ? accS[g][ks][r]*ATT_SCALE : NEG_BIG;
          p[ks*4 + r] = s;
          lmax = fmaxf(lmax, s);
        }
      lmax = fmaxf(lmax, __shfl_xor(lmax, 16));
      lmax = fmaxf(lmax, __shfl_xor(lmax, 32));
      float mnew = fmaxf(m_run[g], lmax);
      alpha[g] = __expf(m_run[g] - mnew);
      m_run[g] = mnew;
      float ls = 0.f;
      #pragma unroll
      for (int i = 0; i < 16; i++){
        float e = __expf(p[i] - mnew);
        p[i] = e; ls += e;
      }
      ls += __shfl_xor(ls, 16);
      ls += __shfl_xor(ls, 32);
      l_run[g] = l_run[g]*alpha[g] + ls;
      #pragma unroll
      for (int ks = 0; ks < 4; ks++){
        u16 pb[4];
        #pragma unroll
        for (int r = 0; r < 4; r++) pb[r] = f2b(p[ks*4 + r]);
        *(uint2*)&Pq[(wq*32 + g*16 + lrw)*APSTR + ks*16 + quad*4] = *(uint2*)pb;
      }
    }

    #pragma unroll
    for (int g = 0; g < 2; g++)
      #pragma unroll
      for (int ds = 0; ds < 8; ds++)
        #pragma unroll
        for (int r = 0; r < 4; r++) accO[g][ds][r] *= alpha[g];

    #pragma unroll
    for (int kks = 0; kks < 2; kks++){
      bf16x8 pf0 = *(const bf16x8*)&Pq[(wq*32      + lrw)*APSTR + kks*32 + quad*8];
      bf16x8 pf1 = *(const bf16x8*)&Pq[(wq*32 + 16 + lrw)*APSTR + kks*32 + quad*8];
      #pragma unroll
      for (int ds = 0; ds < 8; ds++){
        bf16x8 av = *(const bf16x8*)&Vt[(ds*16 + lrw)*AVSTR + kks*32 + quad*8];
        accO[0][ds] = __builtin_amdgcn_mfma_f32_16x16x32_bf16(av, pf0, accO[0][ds], 0, 0, 0);
        accO[1][ds] = __builtin_amdgcn_mfma_f32_16x16x32_bf16(av, pf1, accO[1][ds], 0, 0, 0);
      }
    }
    __syncthreads();
  }

  const float snk = sinks[h];
  #pragma unroll
  for (int g = 0; g < 2; g++){
    float mf = fmaxf(m_run[g], snk);
    float em = __expf(m_run[g] - mf);
    float sc = em / (l_run[g]*em + __expf(snk - mf));
    size_t o = (size_t)(b*S_LEN + qg0 + g*16)*HID + h*HD;
    #pragma unroll
    for (int ds = 0; ds < 8; ds++){
      u16 ob[4];
      #pragma unroll
      for (int r = 0; r < 4; r++) ob[r] = f2b(accO[g][ds][r] * sc);
      *(uint2*)&attnbuf[o + ds*16 + quad*4] = *(uint2*)ob;
    }
  }
}

// ---------------------------------------------------------------------------------------
extern "C" void kernel_launch(void* const* d_in, const int* in_sizes, int n_in,
                              void* d_out, int out_size, void* d_ws, size_t ws_size,
                              hipStream_t stream)
{
  const float* hidden = (const float*)d_in[0];
  const float* wq     = (const float*)d_in[1];
  const float* wkv    = (const float*)d_in[2];
  const float* wgate  = (const float*)d_in[3];
  const float* ape    = (const float*)d_in[4];
  const float* sinks  = (const float*)d_in[5];
  const float* wo     = (const float*)d_in[6];

  const size_t NEED = ((size_t)TOK*HID*2 + (size_t)TOK*512 + (size_t)4*NW*HD
                     + (size_t)HID*HID + (size_t)512*HID) * sizeof(u16); // 87.0 MB

  if (ws_size >= NEED){
    u16* hid_bf = (u16*)d_ws;                         // TOK*HID       (also attnbuf)
    u16* qbuf   = hid_bf + (size_t)TOK*HID;           // TOK*HID
    u16* kvg    = qbuf   + (size_t)TOK*HID;           // TOK*512       (also woT)
    u16* krot   = kvg    + (size_t)TOK*512;           // 2*NW*HD
    u16* vTb    = krot   + (size_t)2*NW*HD;           // 2*HD*NW (transposed V)
    u16* wqT    = vTb    + (size_t)2*NW*HD;           // 2048*2048
    u16* wkvgT  = wqT    + (size_t)HID*HID;           // 512*2048
    u16* attnbuf = hid_bf;
    u16* woT     = kvg;

    cvt_bf16<<<(TOK*HID/8)/256, 256, 0, stream>>>(hidden, hid_bf);
    transpose_w<<<dim3(HID/32, HID/32), 256, 0, stream>>>(wq, wqT, HID, HID);
    transpose_w<<<dim3(256/32, HID/32), 256, 0, stream>>>(wkv,   wkvgT,            HID, 256);
    transpose_w<<<dim3(256/32, HID/32), 256, 0, stream>>>(wgate, wkvgT + (size_t)256*HID, HID, 256);
    gemm256<u16><<<dim3((TOK/256)*(HID/256)), 512, 0, stream>>>(hid_bf, wqT, qbuf, TOK, HID, HID);
    gemm_bf16<u16><<<dim3(512/128, TOK/128), 256, 0, stream>>>(hid_bf, wkvgT, kvg,  TOK, 512, HID);
    pool_rope_k<<<dim3(NW, 2), 128, 0, stream>>>(kvg, kvg + 256, ape, krot, vTb, 512);
    attn_kernel<<<dim3(S_LEN/AQT, NHEAD, 2), 256, 0, stream>>>(qbuf, krot, vTb, sinks, attnbuf);
    transpose_w<<<dim3(HID/32, HID/32), 256, 0, stream>>>(wo, woT, HID, HID);   // kvg dead
    gemm256<float><<<dim3((TOK/256)*(HID/256)), 512, 0, stream>>>(attnbuf, woT, (float*)d_out, TOK, HID, HID);
  } else {
    // fallback: R0 verified GEMM path + attn (RoPE fused in attn; no rope_q)
    u16* qbuf    = (u16*)d_ws;
    u16* kvbuf   = qbuf    + (size_t)TOK*HID;
    u16* gatebuf = kvbuf   + (size_t)TOK*256;
    u16* krot    = gatebuf + (size_t)TOK*256;
    u16* vTb     = krot    + (size_t)2*NW*HD;
    u16* attnbuf = vTb     + (size_t)2*NW*HD;

    gemm_any<float,u16><<<dim3(HID/128, TOK/128), 256, 0, stream>>>(hidden, wq,    qbuf,    TOK, HID, HID);
    gemm_any<float,u16><<<dim3(256/128, TOK/128), 256, 0, stream>>>(hidden, wkv,   kvbuf,   TOK, 256, HID);
    gemm_any<float,u16><<<dim3(256/128, TOK/128), 256, 0, stream>>>(hidden, wgate, gatebuf, TOK, 256, HID);
    pool_rope_k<<<dim3(NW, 2), 128, 0, stream>>>(kvbuf, gatebuf, ape, krot, vTb, 256);
    attn_kernel<<<dim3(S_LEN/AQT, NHEAD, 2), 256, 0, stream>>>(qbuf, krot, vTb, sinks, attnbuf);
    gemm_any<u16,float><<<dim3(HID/128, TOK/128), 256, 0, stream>>>(attnbuf, wo, (float*)d_out, TOK, HID, HID);
  }
}

// Round 9
// 494.552 us; speedup vs baseline: 1.1364x; 1.0116x over previous
//
#include <hip/hip_runtime.h>
#include <math.h>

typedef unsigned short u16;
typedef unsigned int   u32;
typedef __bf16 bf16x8 __attribute__((ext_vector_type(8)));
typedef float  f32x4  __attribute__((ext_vector_type(4)));

#define S_LEN 4096
#define HID   2048
#define NHEAD 16
#define HD    128
#define NW    1024
#define TOK   8192
#define LN10000 9.2103403719761836f
#define NEG_BIG (-1e30f)

__device__ __forceinline__ float b2f(u16 u){
  union { u32 i; float f; } v; v.i = ((u32)u) << 16; return v.f;
}
__device__ __forceinline__ u16 f2b(float f){
  union { float f; u32 i; } v; v.f = f;
  return (u16)((v.i + 0x7FFFu + ((v.i >> 16) & 1u)) >> 16);
}

// ---------------- one-time f32 -> bf16 convert (hidden), 8 elems/thread -----------------
__global__ __launch_bounds__(256) void cvt_bf16(const float* __restrict__ in,
                                                u16* __restrict__ out){
  size_t i = (size_t)blockIdx.x*256 + threadIdx.x;
  float4 a = ((const float4*)in)[2*i];
  float4 b = ((const float4*)in)[2*i+1];
  u16 t[8];
  t[0]=f2b(a.x); t[1]=f2b(a.y); t[2]=f2b(a.z); t[3]=f2b(a.w);
  t[4]=f2b(b.x); t[5]=f2b(b.y); t[6]=f2b(b.z); t[7]=f2b(b.w);
  *(uint4*)&out[i*8] = *(uint4*)t;
}

// ---------------- one-time weight transpose+convert: f32[K][N] -> bf16[N][K] ------------
__global__ __launch_bounds__(256) void transpose_w(const float* __restrict__ in,
    u16* __restrict__ out, int K, int N){
  __shared__ float t[32][33];
  const int n0 = blockIdx.x*32, k0 = blockIdx.y*32;
  const int c = threadIdx.x & 31, r8 = threadIdx.x >> 5;
  #pragma unroll
  for (int i = 0; i < 4; i++)
    t[r8 + i*8][c] = in[(size_t)(k0 + r8 + i*8)*N + n0 + c];
  __syncthreads();
  #pragma unroll
  for (int i = 0; i < 4; i++)
    out[(size_t)(n0 + r8 + i*8)*K + k0 + c] = f2b(t[c][r8 + i*8]);
}

typedef __attribute__((address_space(3))) u16 as3_u16;
typedef __attribute__((address_space(1))) const u16 as1_u16;
__device__ __forceinline__ void gload16(const u16* g, u16* l){
  __builtin_amdgcn_global_load_lds((as1_u16*)g, (as3_u16*)l, 16, 0, 0);
}

// ---------------- 256x256 8-phase GEMM (T2+T3+T4+T5): C = A(M,K) @ Bt(N,K)^T ------------
// Unchanged from R5/R7 (harness-verified).
template<typename TC>
__global__ __launch_bounds__(512, 1) void gemm256(const u16* __restrict__ A,
    const u16* __restrict__ Bt, TC* __restrict__ C, int M, int N, int K)
{
  __shared__ __align__(16) u16 LA[2][256*64];
  __shared__ __align__(16) u16 LB[2][256*64];
  const int tid  = threadIdx.x;
  const int lane = tid & 63;
  const int w    = tid >> 6;        // 0..7
  const int wm   = w & 1;
  const int wn   = w >> 1;          // 0..3
  const int lrw  = lane & 15;
  const int quad = lane >> 4;
  const int NB   = N >> 8;
  const int nwg  = gridDim.x;
  const int bid  = blockIdx.x;
  const int swz  = (bid & 7) * (nwg >> 3) + (bid >> 3);
  const int bN   = (swz % NB) << 8;
  const int bM   = (swz / NB) << 8;

  const int rlo = lane >> 3;
  const int csw = ((lane & 7) ^ rlo) << 3;
  const int sr0 = w * 16;
  const int swr = (lrw & 7) << 3;
  const u16* Ag = A  + (size_t)bM * K + (size_t)rlo * K + csw;
  const u16* Bg = Bt + (size_t)bN * K + (size_t)rlo * K + csw;
  const size_t rK = (size_t)K;

  f32x4 acc[8][4];
  #pragma unroll
  for (int i = 0; i < 8; i++)
    #pragma unroll
    for (int j = 0; j < 4; j++)
      #pragma unroll
      for (int r = 0; r < 4; r++) acc[i][j][r] = 0.f;

  const int NT = K >> 6;

  gload16(Ag + (size_t)(  0 + sr0    )*rK, &LA[0][(  0 + sr0    )*64]);
  gload16(Ag + (size_t)(  0 + sr0 + 8)*rK, &LA[0][(  0 + sr0 + 8)*64]);
  gload16(Bg + (size_t)(  0 + sr0    )*rK, &LB[0][(  0 + sr0    )*64]);
  gload16(Bg + (size_t)(  0 + sr0 + 8)*rK, &LB[0][(  0 + sr0 + 8)*64]);
  gload16(Bg + (size_t)(128 + sr0    )*rK, &LB[0][(128 + sr0    )*64]);
  gload16(Bg + (size_t)(128 + sr0 + 8)*rK, &LB[0][(128 + sr0 + 8)*64]);
  gload16(Ag + (size_t)(128 + sr0    )*rK, &LA[0][(128 + sr0    )*64]);
  gload16(Ag + (size_t)(128 + sr0 + 8)*rK, &LA[0][(128 + sr0 + 8)*64]);
  asm volatile("s_waitcnt vmcnt(2)" ::: "memory");
  __builtin_amdgcn_s_barrier();
  __builtin_amdgcn_sched_barrier(0);

  for (int t = 0; t < NT; ++t){
    const int cur = t & 1, nxt = cur ^ 1;
    const int kn  = ((t + 1) & (NT - 1)) << 6;
    const u16* la = &LA[cur][0];
    const u16* lb = &LB[cur][0];
    u16* sa = &LA[nxt][0];
    u16* sb = &LB[nxt][0];

    bf16x8 bfr[4][2], afr[2][2];

    // ---- phase 0
    gload16(Ag + (size_t)(  0 + sr0    )*rK + kn, &sa[(  0 + sr0    )*64]);
    gload16(Ag + (size_t)(  0 + sr0 + 8)*rK + kn, &sa[(  0 + sr0 + 8)*64]);
    gload16(Bg + (size_t)(  0 + sr0    )*rK + kn, &sb[(  0 + sr0    )*64]);
    gload16(Bg + (size_t)(  0 + sr0 + 8)*rK + kn, &sb[(  0 + sr0 + 8)*64]);
    #pragma unroll
    for (int nf = 0; nf < 4; nf++)
      #pragma unroll
      for (int kh = 0; kh < 2; kh++)
        bfr[nf][kh] = *(const bf16x8*)&lb[(wn*16 + nf*64 + lrw)*64 + ((kh*32 + quad*8) ^ swr)];
    #pragma unroll
    for (int i = 0; i < 2; i++)
      #pragma unroll
      for (int kh = 0; kh < 2; kh++)
        afr[i][kh] = *(const bf16x8*)&la[(wm*16 + (0+i)*32 + lrw)*64 + ((kh*32 + quad*8) ^ swr)];
    __builtin_amdgcn_s_barrier();
    __builtin_amdgcn_sched_barrier(0);
    __builtin_amdgcn_s_setprio(1);
    #pragma unroll
    for (int i = 0; i < 2; i++)
      #pragma unroll
      for (int nf = 0; nf < 4; nf++)
        #pragma unroll
        for (int kh = 0; kh < 2; kh++)
          acc[0+i][nf] = __builtin_amdgcn_mfma_f32_16x16x32_bf16(afr[i][kh], bfr[nf][kh], acc[0+i][nf], 0, 0, 0);
    __builtin_amdgcn_s_setprio(0);
    __builtin_amdgcn_s_barrier();
    __builtin_amdgcn_sched_barrier(0);

    // ---- phase 1
    gload16(Bg + (size_t)(128 + sr0    )*rK + kn, &sb[(128 + sr0    )*64]);
    gload16(Bg + (size_t)(128 + sr0 + 8)*rK + kn, &sb[(128 + sr0 + 8)*64]);
    #pragma unroll
    for (int i = 0; i < 2; i++)
      #pragma unroll
      for (int kh = 0; kh < 2; kh++)
        afr[i][kh] = *(const bf16x8*)&la[(wm*16 + (2+i)*32 + lrw)*64 + ((kh*32 + quad*8) ^ swr)];
    asm volatile("s_waitcnt vmcnt(6)" ::: "memory");
    __builtin_amdgcn_s_barrier();
    __builtin_amdgcn_sched_barrier(0);
    __builtin_amdgcn_s_setprio(1);
    #pragma unroll
    for (int i = 0; i < 2; i++)
      #pragma unroll
      for (int nf = 0; nf < 4; nf++)
        #pragma unroll
        for (int kh = 0; kh < 2; kh++)
          acc[2+i][nf] = __builtin_amdgcn_mfma_f32_16x16x32_bf16(afr[i][kh], bfr[nf][kh], acc[2+i][nf], 0, 0, 0);
    __builtin_amdgcn_s_setprio(0);
    __builtin_amdgcn_s_barrier();
    __builtin_amdgcn_sched_barrier(0);

    // ---- phase 2
    gload16(Ag + (size_t)(128 + sr0    )*rK + kn, &sa[(128 + sr0    )*64]);
    gload16(Ag + (size_t)(128 + sr0 + 8)*rK + kn, &sa[(128 + sr0 + 8)*64]);
    #pragma unroll
    for (int i = 0; i < 2; i++)
      #pragma unroll
      for (int kh = 0; kh < 2; kh++)
        afr[i][kh] = *(const bf16x8*)&la[(wm*16 + (4+i)*32 + lrw)*64 + ((kh*32 + quad*8) ^ swr)];
    __builtin_amdgcn_s_barrier();
    __builtin_amdgcn_sched_barrier(0);
    __builtin_amdgcn_s_setprio(1);
    #pragma unroll
    for (int i = 0; i < 2; i++)
      #pragma unroll
      for (int nf = 0; nf < 4; nf++)
        #pragma unroll
        for (int kh = 0; kh < 2; kh++)
          acc[4+i][nf] = __builtin_amdgcn_mfma_f32_16x16x32_bf16(afr[i][kh], bfr[nf][kh], acc[4+i][nf], 0, 0, 0);
    __builtin_amdgcn_s_setprio(0);
    __builtin_amdgcn_s_barrier();
    __builtin_amdgcn_sched_barrier(0);

    // ---- phase 3
    #pragma unroll
    for (int i = 0; i < 2; i++)
      #pragma unroll
      for (int kh = 0; kh < 2; kh++)
        afr[i][kh] = *(const bf16x8*)&la[(wm*16 + (6+i)*32 + lrw)*64 + ((kh*32 + quad*8) ^ swr)];
    asm volatile("s_waitcnt vmcnt(2)" ::: "memory");
    __builtin_amdgcn_s_barrier();
    __builtin_amdgcn_sched_barrier(0);
    __builtin_amdgcn_s_setprio(1);
    #pragma unroll
    for (int i = 0; i < 2; i++)
      #pragma unroll
      for (int nf = 0; nf < 4; nf++)
        #pragma unroll
        for (int kh = 0; kh < 2; kh++)
          acc[6+i][nf] = __builtin_amdgcn_mfma_f32_16x16x32_bf16(afr[i][kh], bfr[nf][kh], acc[6+i][nf], 0, 0, 0);
    __builtin_amdgcn_s_setprio(0);
    __builtin_amdgcn_s_barrier();
    __builtin_amdgcn_sched_barrier(0);
  }

  asm volatile("s_waitcnt vmcnt(0)" ::: "memory");

  #pragma unroll
  for (int mf = 0; mf < 8; mf++){
    const int orow0 = bM + wm*16 + mf*32 + quad*4;
    #pragma unroll
    for (int nf = 0; nf < 4; nf++){
      const int ocol = bN + wn*16 + nf*64 + lrw;
      #pragma unroll
      for (int r = 0; r < 4; r++){
        size_t idx = (size_t)(orow0 + r)*N + ocol;
        if constexpr (sizeof(TC) == 4) C[idx] = acc[mf][nf][r];
        else                           C[idx] = f2b(acc[mf][nf][r]);
      }
    }
  }
}

// ---------------- m97-structure bf16 GEMM (kept for N=512 kvg) --------------------------
template<typename TC>
__global__ __launch_bounds__(256) void gemm_bf16(const u16* __restrict__ A,
    const u16* __restrict__ Bt, TC* __restrict__ C, int M, int N, int K)
{
  __shared__ u16 As[128*32];
  __shared__ u16 Bs[128*32];
  const int tid  = threadIdx.x;
  const int bM   = blockIdx.y * 128;
  const int bN   = blockIdx.x * 128;
  const int lane = tid & 63;
  const int w    = tid >> 6;
  const int wm   = w >> 1, wn = w & 1;
  const int lrow = lane & 15, quad = lane >> 4;
  const int srow = lane >> 2, skc = (lane & 3) * 8;

  const u16* Ab = &A [(size_t)(bM + w*32 + srow)*K + skc];
  const u16* Bb = &Bt[(size_t)(bN + w*32 + srow)*K + skc];
  const size_t row16 = (size_t)16 * K;

  f32x4 acc[4][4];
  #pragma unroll
  for (int i = 0; i < 4; i++)
    #pragma unroll
    for (int j = 0; j < 4; j++)
      #pragma unroll
      for (int r = 0; r < 4; r++) acc[i][j][r] = 0.f;

  for (int k0 = 0; k0 < K; k0 += 32){
    gload16(Ab + k0,         &As[(w*32     )*32]);
    gload16(Ab + k0 + row16, &As[(w*32 + 16)*32]);
    gload16(Bb + k0,         &Bs[(w*32     )*32]);
    gload16(Bb + k0 + row16, &Bs[(w*32 + 16)*32]);
    __syncthreads();

    bf16x8 af[4], bfv[4];
    #pragma unroll
    for (int mf = 0; mf < 4; mf++)
      af[mf] = *(const bf16x8*)&As[(wm*64 + mf*16 + lrow)*32 + quad*8];
    #pragma unroll
    for (int nf = 0; nf < 4; nf++)
      bfv[nf] = *(const bf16x8*)&Bs[(wn*64 + nf*16 + lrow)*32 + quad*8];
    #pragma unroll
    for (int mf = 0; mf < 4; mf++)
      #pragma unroll
      for (int nf = 0; nf < 4; nf++)
        acc[mf][nf] = __builtin_amdgcn_mfma_f32_16x16x32_bf16(af[mf], bfv[nf], acc[mf][nf], 0, 0, 0);
    __syncthreads();
  }
  #pragma unroll
  for (int mf = 0; mf < 4; mf++){
    #pragma unroll
    for (int nf = 0; nf < 4; nf++){
      int gcol = bN + wn*64 + nf*16 + lrow;
      #pragma unroll
      for (int r = 0; r < 4; r++){
        int grow = bM + wm*64 + mf*16 + quad*4 + r;
        size_t idx = (size_t)grow*N + gcol;
        if constexpr (sizeof(TC) == 4) C[idx] = acc[mf][nf][r];
        else                           C[idx] = f2b(acc[mf][nf][r]);
      }
    }
  }
}

// ---------------- fallback mixed GEMM (harness-verified R0 path) ------------------------
template<typename TA, typename TC>
__global__ __launch_bounds__(256) void gemm_any(const TA* __restrict__ A,
    const float* __restrict__ Bw, TC* __restrict__ C, int M, int N, int K)
{
  __shared__ u16 As[128*40];
  __shared__ u16 Bs[128*40];
  const int tid  = threadIdx.x;
  const int bM   = blockIdx.y * 128;
  const int bN   = blockIdx.x * 128;
  const int lane = tid & 63;
  const int wid  = tid >> 6;
  const int wm   = wid >> 1, wn = wid & 1;
  const int lrow = lane & 15, quad = lane >> 4;

  f32x4 acc[4][4];
  #pragma unroll
  for (int i = 0; i < 4; i++)
    #pragma unroll
    for (int j = 0; j < 4; j++)
      #pragma unroll
      for (int r = 0; r < 4; r++) acc[i][j][r] = 0.f;

  for (int k0 = 0; k0 < K; k0 += 32){
    #pragma unroll
    for (int i = 0; i < 4; i++){
      int c = tid + i*256;
      int row = c >> 3, kc = (c & 7) * 4;
      u16 tmp[4];
      if constexpr (sizeof(TA) == 4){
        float4 v = *(const float4*)&A[(size_t)(bM + row)*K + k0 + kc];
        tmp[0] = f2b(v.x); tmp[1] = f2b(v.y); tmp[2] = f2b(v.z); tmp[3] = f2b(v.w);
      } else {
        *(uint2*)tmp = *(const uint2*)&A[(size_t)(bM + row)*K + k0 + kc];
      }
      *(uint2*)&As[row*40 + kc] = *(uint2*)tmp;
    }
    #pragma unroll
    for (int i = 0; i < 4; i++){
      int c = tid + i*256;
      int kr = c >> 5, nc = (c & 31) * 4;
      float4 v = *(const float4*)&Bw[(size_t)(k0 + kr)*N + bN + nc];
      Bs[(nc+0)*40 + kr] = f2b(v.x);
      Bs[(nc+1)*40 + kr] = f2b(v.y);
      Bs[(nc+2)*40 + kr] = f2b(v.z);
      Bs[(nc+3)*40 + kr] = f2b(v.w);
    }
    __syncthreads();
    bf16x8 af[4], bfv[4];
    #pragma unroll
    for (int mf = 0; mf < 4; mf++)
      af[mf] = *(const bf16x8*)&As[(wm*64 + mf*16 + lrow)*40 + quad*8];
    #pragma unroll
    for (int nf = 0; nf < 4; nf++)
      bfv[nf] = *(const bf16x8*)&Bs[(wn*64 + nf*16 + lrow)*40 + quad*8];
    #pragma unroll
    for (int mf = 0; mf < 4; mf++)
      #pragma unroll
      for (int nf = 0; nf < 4; nf++)
        acc[mf][nf] = __builtin_amdgcn_mfma_f32_16x16x32_bf16(af[mf], bfv[nf], acc[mf][nf], 0, 0, 0);
    __syncthreads();
  }
  #pragma unroll
  for (int mf = 0; mf < 4; mf++){
    #pragma unroll
    for (int nf = 0; nf < 4; nf++){
      int gcol = bN + wn*64 + nf*16 + lrow;
      #pragma unroll
      for (int r = 0; r < 4; r++){
        int grow = bM + wm*64 + mf*16 + quad*4 + r;
        size_t idx = (size_t)grow*N + gcol;
        if constexpr (sizeof(TC) == 4) C[idx] = acc[mf][nf][r];
        else                           C[idx] = f2b(acc[mf][nf][r]);
      }
    }
  }
}

// ---------------- overlapped pooling + k RoPE; V written TRANSPOSED vT[b][d][w] ---------
__global__ void pool_rope_k(const u16* __restrict__ kv, const u16* __restrict__ gate,
                            const float* __restrict__ ape, u16* __restrict__ krot,
                            u16* __restrict__ vT, int str){
  const int d = threadIdx.x;   // 0..127
  const int w = blockIdx.x;    // 0..1023
  const int b = blockIdx.y;
  __shared__ float sh[HD];
  const bool hasprev = (w > 0);
  float gc[4], vc[4], gp[4], vp[4];
  float m = NEG_BIG;
  #pragma unroll
  for (int r = 0; r < 4; r++){
    size_t t = (size_t)(b*S_LEN + w*4 + r)*str;
    vc[r] = b2f(kv[t + 128 + d]);
    gc[r] = b2f(gate[t + 128 + d]) + ape[r*256 + 128 + d];
    m = fmaxf(m, gc[r]);
  }
  if (hasprev){
    #pragma unroll
    for (int r = 0; r < 4; r++){
      size_t t = (size_t)(b*S_LEN + (w-1)*4 + r)*str;
      vp[r] = b2f(kv[t + d]);
      gp[r] = b2f(gate[t + d]) + ape[r*256 + d];
      m = fmaxf(m, gp[r]);
    }
  }
  float s = 0.f, acc = 0.f;
  #pragma unroll
  for (int r = 0; r < 4; r++){
    float e = __expf(gc[r] - m); s += e; acc += e*vc[r];
  }
  if (hasprev){
    #pragma unroll
    for (int r = 0; r < 4; r++){
      float e = __expf(gp[r] - m); s += e; acc += e*vp[r];
    }
  }
  float pooled = acc / s;
  sh[d] = pooled;
  __syncthreads();
  float kr = pooled;
  if (d >= 64){
    int i = (d - 64) >> 1;
    float freq = expf(-(float)i * (LN10000 / 32.f));
    float ang = (float)(4*w) * freq;
    float sn, cs;
    sincosf(ang, &sn, &cs);
    if ((d & 1) == 0) kr = sh[d]*cs - sh[d+1]*sn;
    else              kr = sh[d-1]*sn + sh[d]*cs;
  }
  krot[(size_t)(b*NW + w)*HD + d] = f2b(kr);
  vT[(size_t)(b*HD + d)*NW + w]   = f2b(pooled);   // transposed for attn PV staging
}

// ---------------- MFMA flash attention: DMA-staged K/V (both-sides swizzle) -------------
// Structure = R7 (verified) with staging converted to global_load_lds DMA: LDS linear
// Ks[64][128], Vt[128][64]; per-lane GLOBAL source pre-swizzled (c16 ^= row&7) and frag
// reads swizzled with the same involution (rule 21; pattern = verified gemm256). Removes
// the reg round-trip per chunk, LDS 54.3->50KB (3 blocks/CU). Block-uniform mask-free
// fast path for fully-unmasked chunks; setprio(1) around MFMA clusters (T5).
#define AQT 128
#define AKT 64
#define APSTR 72
#define ATT_SCALE 0.088388347648318447f

__global__ __launch_bounds__(256, 2) void attn_kernel(
    const u16* __restrict__ qbuf, const u16* __restrict__ krot,
    const u16* __restrict__ vT, const float* __restrict__ sinks,
    u16* __restrict__ attnbuf)
{
  __shared__ __align__(16) u16 Ks[AKT*128];   // linear [k][d]  16384 B
  __shared__ __align__(16) u16 Vt[HD*64];     // linear [dv][k] 16384 B
  __shared__ u16 Pq[AQT*APSTR];               // padded [q][k]  18432 B

  const int tid  = threadIdx.x;
  const int q0   = (int)(gridDim.x - 1 - blockIdx.x) * AQT;
  const int h    = blockIdx.y;
  const int b    = blockIdx.z;
  const int lane = tid & 63;
  const int wq   = tid >> 6;
  const int lrw  = lane & 15;
  const int quad = lane >> 4;
  const int qg0  = q0 + wq*32 + lrw;
  const int swl  = lrw & 7;                  // read-side swizzle key (row&7 = lrw&7)

  // staging lane constants: K rows (lane>>4) within 4-row groups, V rows (lane>>3)
  const int krow_l = lane >> 4;              // 0..3
  const int kc16   = lane & 15;
  const int vrow_l = lane >> 3;              // 0..7
  const int vc16   = lane & 7;

  // Q fragments in registers, fused partial interleaved RoPE on d in [64,128)
  bf16x8 qf[2][4];
  #pragma unroll
  for (int g = 0; g < 2; g++){
    const u16* qrow = &qbuf[(size_t)(b*S_LEN + qg0 + g*16)*HID + h*HD];
    qf[g][0] = *(const bf16x8*)&qrow[0*32 + quad*8];
    qf[g][1] = *(const bf16x8*)&qrow[1*32 + quad*8];
    const float pos = (float)(qg0 + g*16);
    #pragma unroll
    for (int d0 = 2; d0 < 4; d0++){
      u16 raw[8];
      *(uint4*)raw = *(const uint4*)&qrow[d0*32 + quad*8];
      u16 outv[8];
      #pragma unroll
      for (int pr = 0; pr < 4; pr++){
        int i = (d0 - 2)*16 + quad*4 + pr;
        float fr = expf(-(float)i * (LN10000/32.f));
        float sn, cs;
        sincosf(pos * fr, &sn, &cs);
        float a  = b2f(raw[2*pr]);
        float bb = b2f(raw[2*pr + 1]);
        outv[2*pr]     = f2b(a*cs - bb*sn);
        outv[2*pr + 1] = f2b(a*sn + bb*cs);
      }
      qf[g][d0] = *(bf16x8*)outv;
    }
  }

  float m_run[2] = {NEG_BIG, NEG_BIG};
  float l_run[2] = {0.f, 0.f};
  f32x4 accO[2][8];
  #pragma unroll
  for (int g = 0; g < 2; g++)
    #pragma unroll
    for (int ds = 0; ds < 8; ds++)
      #pragma unroll
      for (int r = 0; r < 4; r++) accO[g][ds][r] = 0.f;

  const int kmax_tile = (q0 + AQT - 1 - 3) >> 2;
  int nchunk = (kmax_tile >> 6) + 1;
  if (nchunk > NW/AKT) nchunk = NW/AKT;

  for (int ch = 0; ch < nchunk; ch++){
    const int kc0 = ch * AKT;
    // DMA stage K: wave wq stages rows [wq*16, wq*16+16), 4 rows / 1KB per call.
    // LDS dest linear (wave-uniform base + lane*16); global source column pre-swizzled.
    #pragma unroll
    for (int i = 0; i < 4; i++){
      int row = wq*16 + i*4 + krow_l;
      int c16s = kc16 ^ (row & 7);
      gload16(&krot[(size_t)(b*NW + kc0 + row)*HD + c16s*8], &Ks[(wq*16 + i*4)*128]);
    }
    // DMA stage V: wave wq stages rows [wq*32, wq*32+32), 8 rows / 1KB per call.
    #pragma unroll
    for (int i = 0; i < 4; i++){
      int row = wq*32 + i*8 + vrow_l;
      int c16s = vc16 ^ (row & 7);
      gload16(&vT[(size_t)(b*HD + row)*NW + kc0 + c16s*8], &Vt[(wq*32 + i*8)*64]);
    }
    __syncthreads();   // compiler drains vmcnt before barrier

    // QK^T swapped (reads swizzled with the same involution)
    f32x4 accS[2][4];
    #pragma unroll
    for (int g = 0; g < 2; g++)
      #pragma unroll
      for (int ks = 0; ks < 4; ks++)
        #pragma unroll
        for (int r = 0; r < 4; r++) accS[g][ks][r] = 0.f;
    __builtin_amdgcn_s_setprio(1);
    #pragma unroll
    for (int d0 = 0; d0 < 4; d0++){
      #pragma unroll
      for (int ks = 0; ks < 4; ks++){
        bf16x8 kf = *(const bf16x8*)&Ks[(ks*16 + lrw)*128 + (((4*d0 + quad) ^ swl) << 3)];
        accS[0][ks] = __builtin_amdgcn_mfma_f32_16x16x32_bf16(kf, qf[0][d0], accS[0][ks], 0, 0, 0);
        accS[1][ks] = __builtin_amdgcn_mfma_f32_16x16x32_bf16(kf, qf[1][d0], accS[1][ks], 0, 0, 0);
      }
    }
    __builtin_amdgcn_s_setprio(0);

    // register softmax; mask only on chunks that need it (block-uniform branch)
    const bool needmask = (q0 < 4*(kc0 + AKT - 1) + 3);
    float alpha[2];
    #pragma unroll
    for (int g = 0; g < 2; g++){
      const int qg = qg0 + g*16;
      float p[16];
      float lmax = NEG_BIG;
      if (needmask){
        #pragma unroll
        for (int ks = 0; ks < 4; ks++)
          #pragma unroll
          for (int r = 0; r < 4; r++){
            int kg = kc0 + ks*16 + quad*4 + r;
            float s = (qg >= 4*kg + 3) ? accS[g][ks][r]*ATT_SCALE : NEG_BIG;
            p[ks*4 + r] = s;
            lmax = fmaxf(lmax, s);
          }
      } else {
        #pragma unroll
        for (int ks = 0; ks < 4; ks++)
          #pragma unroll
          for (int r = 0; r < 4; r++){
            float s = accS[g][ks][r]*ATT_SCALE;
            p[ks*4 + r] = s;
            lmax = fmaxf(lmax, s);
          }
      }
      lmax = fmaxf(lmax, __shfl_xor(lmax, 16));
      lmax = fmaxf(lmax, __shfl_xor(lmax, 32));
      float mnew = fmaxf(m_run[g], lmax);
      alpha[g] = __expf(m_run[g] - mnew);
      m_run[g] = mnew;
      float ls = 0.f;
      #pragma unroll
      for (int i = 0; i < 16; i++){
        float e = __expf(p[i] - mnew);
        p[i] = e; ls += e;
      }
      ls += __shfl_xor(ls, 16);
      ls += __shfl_xor(ls, 32);
      l_run[g] = l_run[g]*alpha[g] + ls;
      #pragma unroll
      for (int ks = 0; ks < 4; ks++){
        u16 pb[4];
        #pragma unroll
        for (int r = 0; r < 4; r++) pb[r] = f2b(p[ks*4 + r]);
        *(uint2*)&Pq[(wq*32 + g*16 + lrw)*APSTR + ks*16 + quad*4] = *(uint2*)pb;
      }
    }

    #pragma unroll
    for (int g = 0; g < 2; g++)
      #pragma unroll
      for (int ds = 0; ds < 8; ds++)
        #pragma unroll
        for (int r = 0; r < 4; r++) accO[g][ds][r] *= alpha[g];

    // PV swapped (Vt reads swizzled)
    __builtin_amdgcn_s_setprio(1);
    #pragma unroll
    for (int kks = 0; kks < 2; kks++){
      bf16x8 pf0 = *(const bf16x8*)&Pq[(wq*32      + lrw)*APSTR + kks*32 + quad*8];
      bf16x8 pf1 = *(const bf16x8*)&Pq[(wq*32 + 16 + lrw)*APSTR + kks*32 + quad*8];
      #pragma unroll
      for (int ds = 0; ds < 8; ds++){
        bf16x8 av = *(const bf16x8*)&Vt[(ds*16 + lrw)*64 + (((kks*4 + quad) ^ swl) << 3)];
        accO[0][ds] = __builtin_amdgcn_mfma_f32_16x16x32_bf16(av, pf0, accO[0][ds], 0, 0, 0);
        accO[1][ds] = __builtin_amdgcn_mfma_f32_16x16x32_bf16(av, pf1, accO[1][ds], 0, 0, 0);
      }
    }
    __builtin_amdgcn_s_setprio(0);
    __syncthreads();
  }

  const float snk = sinks[h];
  #pragma unroll
  for (int g = 0; g < 2; g++){
    float mf = fmaxf(m_run[g], snk);
    float em = __expf(m_run[g] - mf);
    float sc = em / (l_run[g]*em + __expf(snk - mf));
    size_t o = (size_t)(b*S_LEN + qg0 + g*16)*HID + h*HD;
    #pragma unroll
    for (int ds = 0; ds < 8; ds++){
      u16 ob[4];
      #pragma unroll
      for (int r = 0; r < 4; r++) ob[r] = f2b(accO[g][ds][r] * sc);
      *(uint2*)&attnbuf[o + ds*16 + quad*4] = *(uint2*)ob;
    }
  }
}

// ---------------------------------------------------------------------------------------
extern "C" void kernel_launch(void* const* d_in, const int* in_sizes, int n_in,
                              void* d_out, int out_size, void* d_ws, size_t ws_size,
                              hipStream_t stream)
{
  const float* hidden = (const float*)d_in[0];
  const float* wq     = (const float*)d_in[1];
  const float* wkv    = (const float*)d_in[2];
  const float* wgate  = (const float*)d_in[3];
  const float* ape    = (const float*)d_in[4];
  const float* sinks  = (const float*)d_in[5];
  const float* wo     = (const float*)d_in[6];

  const size_t NEED = ((size_t)TOK*HID*2 + (size_t)TOK*512 + (size_t)4*NW*HD
                     + (size_t)HID*HID + (size_t)512*HID) * sizeof(u16); // 87.0 MB

  if (ws_size >= NEED){
    u16* hid_bf = (u16*)d_ws;                         // TOK*HID       (also attnbuf)
    u16* qbuf   = hid_bf + (size_t)TOK*HID;           // TOK*HID
    u16* kvg    = qbuf   + (size_t)TOK*HID;           // TOK*512       (also woT)
    u16* krot   = kvg    + (size_t)TOK*512;           // 2*NW*HD
    u16* vTb    = krot   + (size_t)2*NW*HD;           // 2*HD*NW (transposed V)
    u16* wqT    = vTb    + (size_t)2*NW*HD;           // 2048*2048
    u16* wkvgT  = wqT    + (size_t)HID*HID;           // 512*2048
    u16* attnbuf = hid_bf;
    u16* woT     = kvg;

    cvt_bf16<<<(TOK*HID/8)/256, 256, 0, stream>>>(hidden, hid_bf);
    transpose_w<<<dim3(HID/32, HID/32), 256, 0, stream>>>(wq, wqT, HID, HID);
    transpose_w<<<dim3(256/32, HID/32), 256, 0, stream>>>(wkv,   wkvgT,            HID, 256);
    transpose_w<<<dim3(256/32, HID/32), 256, 0, stream>>>(wgate, wkvgT + (size_t)256*HID, HID, 256);
    gemm256<u16><<<dim3((TOK/256)*(HID/256)), 512, 0, stream>>>(hid_bf, wqT, qbuf, TOK, HID, HID);
    gemm_bf16<u16><<<dim3(512/128, TOK/128), 256, 0, stream>>>(hid_bf, wkvgT, kvg,  TOK, 512, HID);
    pool_rope_k<<<dim3(NW, 2), 128, 0, stream>>>(kvg, kvg + 256, ape, krot, vTb, 512);
    attn_kernel<<<dim3(S_LEN/AQT, NHEAD, 2), 256, 0, stream>>>(qbuf, krot, vTb, sinks, attnbuf);
    transpose_w<<<dim3(HID/32, HID/32), 256, 0, stream>>>(wo, woT, HID, HID);   // kvg dead
    gemm256<float><<<dim3((TOK/256)*(HID/256)), 512, 0, stream>>>(attnbuf, woT, (float*)d_out, TOK, HID, HID);
  } else {
    // fallback: R0 verified GEMM path + attn (RoPE fused in attn; no rope_q)
    u16* qbuf    = (u16*)d_ws;
    u16* kvbuf   = qbuf    + (size_t)TOK*HID;
    u16* gatebuf = kvbuf   + (size_t)TOK*256;
    u16* krot    = gatebuf + (size_t)TOK*256;
    u16* vTb     = krot    + (size_t)2*NW*HD;
    u16* attnbuf = vTb     + (size_t)2*NW*HD;

    gemm_any<float,u16><<<dim3(HID/128, TOK/128), 256, 0, stream>>>(hidden, wq,    qbuf,    TOK, HID, HID);
    gemm_any<float,u16><<<dim3(256/128, TOK/128), 256, 0, stream>>>(hidden, wkv,   kvbuf,   TOK, 256, HID);
    gemm_any<float,u16><<<dim3(256/128, TOK/128), 256, 0, stream>>>(hidden, wgate, gatebuf, TOK, 256, HID);
    pool_rope_k<<<dim3(NW, 2), 128, 0, stream>>>(kvbuf, gatebuf, ape, krot, vTb, 256);
    attn_kernel<<<dim3(S_LEN/AQT, NHEAD, 2), 256, 0, stream>>>(qbuf, krot, vTb, sinks, attnbuf);
    gemm_any<u16,float><<<dim3(HID/128, TOK/128), 256, 0, stream>>>(attnbuf, wo, (float*)d_out, TOK, HID, HID);
  }
}